// Round 3
// baseline (36141.870 us; speedup 1.0000x reference)
//
#include <hip/hip_runtime.h>
#include <math.h>

#define B_ 64
#define T_ 32
#define S_ 64
#define E_ 512
#define H_ 1024
#define C_ 2048
#define G_ 3072
#define NBLK 256

typedef __bf16 bf16_t;
typedef bf16_t bf16x8 __attribute__((ext_vector_type(8)));
typedef float f32x4 __attribute__((ext_vector_type(4)));

__device__ __forceinline__ float sigm_(float x) { return 1.f / (1.f + __expf(-x)); }
__device__ __forceinline__ float tanh_(float x) { return 1.f - 2.f / (__expf(2.f * x) + 1.f); }

// ===================== fused f32 -> bf16 converter =====================
struct SegPack {
    const float* s[8];
    bf16_t* d[8];
    int cum[9];   // cumulative chunk (8-elem) counts
};

__global__ __launch_bounds__(256)
void cvt_multi(SegPack p)
{
    int gid = blockIdx.x * 256 + threadIdx.x;
    if (gid >= p.cum[8]) return;
    int seg = 0;
    #pragma unroll
    for (int k = 1; k < 8; ++k) if (gid >= p.cum[k]) seg = k;
    int i = gid - p.cum[seg];
    const float4* s4 = (const float4*)p.s[seg];
    float4 a = s4[2 * i], b = s4[2 * i + 1];
    bf16x8 o;
    o[0] = (bf16_t)a.x; o[1] = (bf16_t)a.y; o[2] = (bf16_t)a.z; o[3] = (bf16_t)a.w;
    o[4] = (bf16_t)b.x; o[5] = (bf16_t)b.y; o[6] = (bf16_t)b.z; o[7] = (bf16_t)b.w;
    ((bf16x8*)p.d[seg])[i] = o;
}

// transpose + convert: out[c][r] = (bf16) in[r][c]
__global__ __launch_bounds__(1024)
void transpose_cvt(const float* __restrict__ in, bf16_t* __restrict__ out, int R, int Cc)
{
    __shared__ float tsh[32][33];
    int c0 = blockIdx.x * 32, r0 = blockIdx.y * 32;
    tsh[threadIdx.y][threadIdx.x] = in[(size_t)(r0 + threadIdx.y) * Cc + c0 + threadIdx.x];
    __syncthreads();
    out[(size_t)(c0 + threadIdx.y) * R + r0 + threadIdx.x] = (bf16_t)tsh[threadIdx.x][threadIdx.y];
}

// embedding lookup -> bf16
__global__ __launch_bounds__(256)
void embed_cvt(const int* __restrict__ y, const float* __restrict__ emb, bf16_t* __restrict__ xb)
{
    int i = blockIdx.x * 256 + threadIdx.x;   // over B*T*E/8 = 131072
    int row = i >> 6, c8 = i & 63;
    const float4* s4 = (const float4*)(emb + (size_t)y[row] * E_) + c8 * 2;
    float4 a = s4[0], b = s4[1];
    bf16x8 o;
    o[0] = (bf16_t)a.x; o[1] = (bf16_t)a.y; o[2] = (bf16_t)a.z; o[3] = (bf16_t)a.w;
    o[4] = (bf16_t)b.x; o[5] = (bf16_t)b.y; o[6] = (bf16_t)b.z; o[7] = (bf16_t)b.w;
    ((bf16x8*)xb)[i] = o;
}

// ===================== bf16 MFMA GEMM: out[m,n] = sum_k A[m,k]*Wt[n,k] ====
// A [M,K] bf16 row-major, Wt [N,K] bf16 row-major. Tile 128x128, BK=32.
#define LSTR 80   // LDS row stride in bytes (64 data + 16 pad -> conflict-free)

template<int ACCUM, int OUTBF>
__global__ __launch_bounds__(256)
void bgemm(const bf16_t* __restrict__ A, const bf16_t* __restrict__ Wt,
           void* __restrict__ outv, int N, int K)
{
    __shared__ char As[128 * LSTR];
    __shared__ char Bs[128 * LSTR];
    const int tid = threadIdx.x;
    const int lane = tid & 63, wave = tid >> 6;
    const int m0 = blockIdx.y * 128, n0 = blockIdx.x * 128;
    const int wm = (wave & 1) * 64, wn = (wave >> 1) * 64;
    const int l15 = lane & 15, l4 = lane >> 4;
    const int r0 = tid >> 2, c0 = tid & 3;

    f32x4 acc[4][4] = {};

    for (int k0 = 0; k0 < K; k0 += 32) {
        #pragma unroll
        for (int p = 0; p < 2; ++p) {
            int row = r0 + p * 64;
            *(bf16x8*)(As + row * LSTR + c0 * 16) =
                *(const bf16x8*)(A + (size_t)(m0 + row) * K + k0 + c0 * 8);
            *(bf16x8*)(Bs + row * LSTR + c0 * 16) =
                *(const bf16x8*)(Wt + (size_t)(n0 + row) * K + k0 + c0 * 8);
        }
        __syncthreads();
        bf16x8 af[4], bfr[4];
        #pragma unroll
        for (int i = 0; i < 4; ++i)
            af[i] = *(const bf16x8*)(As + (wm + i * 16 + l15) * LSTR + l4 * 16);
        #pragma unroll
        for (int j = 0; j < 4; ++j)
            bfr[j] = *(const bf16x8*)(Bs + (wn + j * 16 + l15) * LSTR + l4 * 16);
        #pragma unroll
        for (int i = 0; i < 4; ++i)
            #pragma unroll
            for (int j = 0; j < 4; ++j)
                acc[i][j] = __builtin_amdgcn_mfma_f32_16x16x32_bf16(af[i], bfr[j], acc[i][j], 0, 0, 0);
        __syncthreads();
    }

    #pragma unroll
    for (int i = 0; i < 4; ++i)
        #pragma unroll
        for (int j = 0; j < 4; ++j)
            #pragma unroll
            for (int r = 0; r < 4; ++r) {
                int m = m0 + wm + i * 16 + l4 * 4 + r;
                int n = n0 + wn + j * 16 + l15;
                float v = acc[i][j][r];
                if (OUTBF) {
                    ((bf16_t*)outv)[(size_t)m * N + n] = (bf16_t)v;
                } else {
                    float* out = (float*)outv;
                    if (ACCUM) out[(size_t)m * N + n] += v;
                    else       out[(size_t)m * N + n] = v;
                }
            }
}

// ===================== persistent scan kernel =====================
#define SM_W1 0
#define SM_W2 32768
#define SM_W3 65536
#define SM_QB 131072
#define SM_VS 135168
#define SM_PR 139264
#define SM_SC 139520
#define SMEM_BYTES 139776

__device__ __forceinline__ void gbar(unsigned* cnt, unsigned& target)
{
    __syncthreads();
    if (threadIdx.x == 0) {
        __threadfence();
        __hip_atomic_fetch_add(cnt, 1u, __ATOMIC_RELEASE, __HIP_MEMORY_SCOPE_AGENT);
        target += NBLK;
        while (__hip_atomic_load(cnt, __ATOMIC_ACQUIRE, __HIP_MEMORY_SCOPE_AGENT) < target)
            __builtin_amdgcn_s_sleep(8);
        __threadfence();
    }
    __syncthreads();
}

__global__ __launch_bounds__(256, 1)
void scan_kernel(
    const bf16_t* __restrict__ Whh1b, const bf16_t* __restrict__ Whh2b,
    const bf16_t* __restrict__ WqTb,  const bf16_t* __restrict__ Wih2b,
    const bf16_t* __restrict__ Xg,
    const float* __restrict__ b_ih1, const float* __restrict__ b_hh1,
    const float* __restrict__ b_ih2, const float* __restrict__ b_hh2,
    const float* __restrict__ bq,    const float* __restrict__ v_attn,
    const int*   __restrict__ cmask,
    const float* __restrict__ hidden,
    const float* __restrict__ cacheK, const bf16_t* __restrict__ ctxb,
    float* __restrict__ qg, float* __restrict__ hf,
    bf16_t* __restrict__ hb, bf16_t* __restrict__ h1b,
    bf16_t* __restrict__ attnseq, bf16_t* __restrict__ outseq,
    float* __restrict__ hfinal,
    unsigned* __restrict__ bar)
{
    extern __shared__ char sm[];
    const int tid = threadIdx.x, blk = blockIdx.x;
    const int lane = tid & 63, wave = tid >> 6;
    const int l15 = lane & 15, l4 = lane >> 4;
    const int blk4 = blk * 4;

    // ---- stage weight slices into LDS (swizzled) ----
    for (int e = tid; e < 16 * 128; e += 256) {            // W_hh1: 12 rows + 4 zero
        int r = e >> 7, c = e & 127;
        bf16x8 v; 
        #pragma unroll
        for (int q = 0; q < 8; ++q) v[q] = (bf16_t)0.f;
        if (r < 12)
            v = *(const bf16x8*)(Whh1b + (size_t)((r >> 2) * 1024 + blk4 + (r & 3)) * 1024 + c * 8);
        *(bf16x8*)(sm + SM_W1 + r * 2048 + ((c * 16) ^ ((r & 7) << 4))) = v;
    }
    for (int e = tid; e < 16 * 128; e += 256) {            // W_hh2 gates + WqT rows
        int r = e >> 7, c = e & 127;
        const bf16_t* src = (r < 12)
            ? Whh2b + (size_t)((r >> 2) * 1024 + blk4 + (r & 3)) * 1024
            : WqTb + (size_t)(blk4 + r - 12) * 1024;
        *(bf16x8*)(sm + SM_W2 + r * 2048 + ((c * 16) ^ ((r & 7) << 4))) =
            *(const bf16x8*)(src + c * 8);
    }
    for (int e = tid; e < 16 * 256; e += 256) {            // W_ih2: 12 rows + 4 zero, K=2048
        int r = e >> 8, c = e & 255;
        bf16x8 v;
        #pragma unroll
        for (int q = 0; q < 8; ++q) v[q] = (bf16_t)0.f;
        if (r < 12)
            v = *(const bf16x8*)(Wih2b + (size_t)((r >> 2) * 1024 + blk4 + (r & 3)) * 2048 + c * 8);
        *(bf16x8*)(sm + SM_W3 + r * 4096 + ((c * 16) ^ ((r & 7) << 4))) = v;
    }
    float* vs = (float*)(sm + SM_VS);
    for (int i = tid; i < 1024; i += 256) vs[i] = v_attn[i];

    {   // h init
        int idx = blk * 256 + tid;
        float hv = hidden[idx];
        hf[idx] = hv;
        hb[idx] = (bf16_t)hv;
    }

    unsigned target = 0;
    gbar(bar, target);

    float* qb  = (float*)(sm + SM_QB);
    float* pr  = (float*)(sm + SM_PR);
    float* scb = (float*)(sm + SM_SC);

    for (int t = 0; t < T_; ++t) {
        // ===== P0: gh1 = h @ W_hh1^T (slice) + in-register GRU1 =====
        f32x4 acc0 = {0.f, 0.f, 0.f, 0.f};
        {
            const char* abase = (const char*)hb + (size_t)(wave * 16 + l15) * 2048;
            #pragma unroll 16
            for (int kk = 0; kk < 32; ++kk) {
                bf16x8 av = *(const bf16x8*)(abase + kk * 64 + l4 * 16);
                bf16x8 bv = *(const bf16x8*)(sm + SM_W1 + l15 * 2048 + ((kk * 64 + l4 * 16) ^ ((l15 & 7) << 4)));
                acc0 = __builtin_amdgcn_mfma_f32_16x16x32_bf16(av, bv, acc0, 0, 0, 0);
            }
        }
        float h1r_[4] = {0.f, 0.f, 0.f, 0.f};
        #pragma unroll
        for (int r2 = 0; r2 < 4; ++r2) {
            float gr = acc0[r2];
            float gz = __shfl(acc0[r2], (lane & 48) | (l15 + 4), 64);
            float gn = __shfl(acc0[r2], (lane & 48) | (l15 + 8), 64);
            if (l15 < 4) {
                int j = blk4 + l15;
                int b = wave * 16 + l4 * 4 + r2;
                const bf16_t* xg = Xg + ((size_t)b * T_ + t) * 3072;
                float rr = sigm_((float)xg[j]          + b_ih1[j]          + gr + b_hh1[j]);
                float zz = sigm_((float)xg[1024 + j]   + b_ih1[1024 + j]   + gz + b_hh1[1024 + j]);
                float nn = tanh_((float)xg[2048 + j]   + b_ih1[2048 + j]   + rr * (gn + b_hh1[2048 + j]));
                float h1v = (1.f - zz) * nn + zz * hf[b * 1024 + j];
                h1r_[r2] = h1v;
                h1b[b * 1024 + j] = (bf16_t)h1v;
            }
        }
        gbar(bar, target);

        // ===== P1: [gh2 | q] = h1 @ [W_hh2 ; WqT]^T (slice) =====
        f32x4 acc1 = {0.f, 0.f, 0.f, 0.f};
        {
            const char* abase = (const char*)h1b + (size_t)(wave * 16 + l15) * 2048;
            #pragma unroll 16
            for (int kk = 0; kk < 32; ++kk) {
                bf16x8 av = *(const bf16x8*)(abase + kk * 64 + l4 * 16);
                bf16x8 bv = *(const bf16x8*)(sm + SM_W2 + l15 * 2048 + ((kk * 64 + l4 * 16) ^ ((l15 & 7) << 4)));
                acc1 = __builtin_amdgcn_mfma_f32_16x16x32_bf16(av, bv, acc1, 0, 0, 0);
            }
        }
        if (l15 >= 12) {
            int jq = blk4 + l15 - 12;
            #pragma unroll
            for (int r2 = 0; r2 < 4; ++r2)
                qg[(wave * 16 + l4 * 4 + r2) * 1024 + jq] = acc1[r2];
        }
        gbar(bar, target);

        // ===== P2: attention (blocks 0..63, one batch row each) =====
        if (blk < 64) {
            const int b = blk;
            for (int i = tid; i < 1024; i += 256) qb[i] = qg[b * 1024 + i] + bq[i];
            __syncthreads();
            for (int s = wave; s < 64; s += 4) {
                const float* ck = cacheK + ((size_t)b * 64 + s) * 1024;
                float sum = 0.f;
                for (int k = lane; k < 1024; k += 64)
                    sum += tanh_(qb[k] + ck[k]) * vs[k];
                #pragma unroll
                for (int off = 32; off; off >>= 1) sum += __shfl_down(sum, off, 64);
                if (lane == 0) scb[s] = sum;
            }
            __syncthreads();
            if (wave == 0) {
                float v = (cmask[b * 64 + lane] != 0) ? -3.4e38f : scb[lane];
                float mx = v;
                #pragma unroll
                for (int off = 32; off; off >>= 1) mx = fmaxf(mx, __shfl_xor(mx, off, 64));
                float e = __expf(v - mx);
                float sden = e;
                #pragma unroll
                for (int off = 32; off; off >>= 1) sden += __shfl_xor(sden, off, 64);
                pr[lane] = e / sden;
            }
            __syncthreads();
            #pragma unroll
            for (int i = 0; i < 8; ++i) {
                int c = tid + 256 * i;
                const bf16_t* cb = ctxb + (size_t)b * 64 * 2048 + c;
                float sum = 0.f;
                #pragma unroll 8
                for (int s = 0; s < 64; ++s) sum += pr[s] * (float)cb[(size_t)s * 2048];
                attnseq[((size_t)b * T_ + t) * 2048 + c] = (bf16_t)sum;
            }
        }
        gbar(bar, target);

        // ===== P3: gi2 = attn @ W_ih2^T (slice) + in-register GRU2 =====
        f32x4 acc3 = {0.f, 0.f, 0.f, 0.f};
        {
            const char* abase = (const char*)attnseq + (((size_t)(wave * 16 + l15)) * T_ + t) * 4096;
            #pragma unroll 16
            for (int kk = 0; kk < 64; ++kk) {
                bf16x8 av = *(const bf16x8*)(abase + kk * 64 + l4 * 16);
                bf16x8 bv = *(const bf16x8*)(sm + SM_W3 + l15 * 4096 + ((kk * 64 + l4 * 16) ^ ((l15 & 7) << 4)));
                acc3 = __builtin_amdgcn_mfma_f32_16x16x32_bf16(av, bv, acc3, 0, 0, 0);
            }
        }
        #pragma unroll
        for (int r2 = 0; r2 < 4; ++r2) {
            float ir  = acc3[r2];
            float iz  = __shfl(acc3[r2], (lane & 48) | (l15 + 4), 64);
            float in2 = __shfl(acc3[r2], (lane & 48) | (l15 + 8), 64);
            float hr  = acc1[r2];
            float hz  = __shfl(acc1[r2], (lane & 48) | (l15 + 4), 64);
            float hn  = __shfl(acc1[r2], (lane & 48) | (l15 + 8), 64);
            if (l15 < 4) {
                int j = blk4 + l15;
                int b = wave * 16 + l4 * 4 + r2;
                float rr = sigm_(ir + b_ih2[j]          + hr + b_hh2[j]);
                float zz = sigm_(iz + b_ih2[1024 + j]   + hz + b_hh2[1024 + j]);
                float nn = tanh_(in2 + b_ih2[2048 + j]  + rr * (hn + b_hh2[2048 + j]));
                float h2 = (1.f - zz) * nn + zz * h1r_[r2];
                hf[b * 1024 + j] = h2;
                hb[b * 1024 + j] = (bf16_t)h2;
                outseq[((size_t)b * T_ + t) * 1024 + j] = (bf16_t)h2;
                if (t == T_ - 1) hfinal[b * 1024 + j] = h2;
            }
        }
        gbar(bar, target);
    }
}

// ===================== final logits =====================
__global__ __launch_bounds__(256)
void final_kernel(const float* __restrict__ Lacc,
                  const float* __restrict__ bi, const float* __restrict__ bh,
                  const float* __restrict__ bc, float* __restrict__ out)
{
    int i = blockIdx.x * 256 + threadIdx.x;
    int e = i & 511;
    out[i] = tanh_(Lacc[i] + bi[e] + bh[e] + bc[e]);
}

// ===================== host =====================
extern "C" void kernel_launch(void* const* d_in, const int* in_sizes, int n_in,
                              void* d_out, int out_size, void* d_ws, size_t ws_size,
                              hipStream_t stream)
{
    const int*   y       = (const int*)  d_in[0];
    const float* context = (const float*)d_in[1];
    const int*   cmask   = (const int*)  d_in[2];
    const float* hidden  = (const float*)d_in[3];
    const float* emb     = (const float*)d_in[4];
    const float* W_ih1   = (const float*)d_in[5];
    const float* W_hh1   = (const float*)d_in[6];
    const float* b_ih1   = (const float*)d_in[7];
    const float* b_hh1   = (const float*)d_in[8];
    const float* Wq      = (const float*)d_in[9];
    const float* bq      = (const float*)d_in[10];
    const float* Wk      = (const float*)d_in[11];
    const float* v_attn  = (const float*)d_in[12];
    const float* W_ih2   = (const float*)d_in[13];
    const float* W_hh2   = (const float*)d_in[14];
    const float* b_ih2   = (const float*)d_in[15];
    const float* b_hh2   = (const float*)d_in[16];
    const float* Wi      = (const float*)d_in[17];
    const float* bi      = (const float*)d_in[18];
    const float* Wh      = (const float*)d_in[19];
    const float* bh      = (const float*)d_in[20];
    const float* Wc      = (const float*)d_in[21];
    const float* bc      = (const float*)d_in[22];

    char* ws = (char*)d_ws;
    size_t o = 0;
    auto alloc = [&](size_t bytes) { char* p = ws + o; o += (bytes + 255) & ~(size_t)255; return p; };
    unsigned* bar   = (unsigned*)alloc(256);
    bf16_t* x_b     = (bf16_t*)alloc((size_t)2048 * 512 * 2);
    bf16_t* Wih1b   = (bf16_t*)alloc((size_t)3072 * 512 * 2);
    bf16_t* Wib     = (bf16_t*)alloc((size_t)512 * 512 * 2);
    bf16_t* WkTb    = (bf16_t*)alloc((size_t)1024 * 2048 * 2);
    bf16_t* WqTb    = (bf16_t*)alloc((size_t)1024 * 1024 * 2);
    bf16_t* Whh1b   = (bf16_t*)alloc((size_t)3072 * 1024 * 2);
    bf16_t* Whh2b   = (bf16_t*)alloc((size_t)3072 * 1024 * 2);
    bf16_t* Wih2b   = (bf16_t*)alloc((size_t)3072 * 2048 * 2);
    bf16_t* Whb     = (bf16_t*)alloc((size_t)512 * 1024 * 2);
    bf16_t* Wcb     = (bf16_t*)alloc((size_t)512 * 2048 * 2);
    bf16_t* ctxb    = (bf16_t*)alloc((size_t)4096 * 2048 * 2);
    bf16_t* Xgb     = (bf16_t*)alloc((size_t)2048 * 3072 * 2);
    float*  Lacc    = (float*) alloc((size_t)2048 * 512 * 4);
    float*  cacheK  = (float*) alloc((size_t)4096 * 1024 * 4);
    float*  qg      = (float*) alloc((size_t)64 * 1024 * 4);
    float*  hf      = (float*) alloc((size_t)64 * 1024 * 4);
    bf16_t* hb      = (bf16_t*)alloc((size_t)64 * 1024 * 2);
    bf16_t* h1b     = (bf16_t*)alloc((size_t)64 * 1024 * 2);
    bf16_t* attnseq = (bf16_t*)alloc((size_t)2048 * 2048 * 2);
    bf16_t* outseq  = (bf16_t*)alloc((size_t)2048 * 1024 * 2);

    hipMemsetAsync(bar, 0, 256, stream);

    // fused weight conversions
    SegPack sp;
    int n8[8] = {3072 * 512 / 8, 512 * 512 / 8, 3072 * 1024 / 8, 3072 * 1024 / 8,
                 3072 * 2048 / 8, 512 * 1024 / 8, 512 * 2048 / 8, 4096 * 2048 / 8};
    const float* srcs[8] = {W_ih1, Wi, W_hh1, W_hh2, W_ih2, Wh, Wc, context};
    bf16_t* dsts[8] = {Wih1b, Wib, Whh1b, Whh2b, Wih2b, Whb, Wcb, ctxb};
    sp.cum[0] = 0;
    for (int k = 0; k < 8; ++k) { sp.s[k] = srcs[k]; sp.d[k] = dsts[k]; sp.cum[k + 1] = sp.cum[k] + n8[k]; }
    cvt_multi<<<(sp.cum[8] + 255) / 256, 256, 0, stream>>>(sp);

    transpose_cvt<<<dim3(1024 / 32, 2048 / 32), dim3(32, 32), 0, stream>>>(Wk, WkTb, 2048, 1024);
    transpose_cvt<<<dim3(1024 / 32, 1024 / 32), dim3(32, 32), 0, stream>>>(Wq, WqTb, 1024, 1024);
    embed_cvt<<<512, 256, 0, stream>>>(y, emb, x_b);

    // prologue GEMMs (bf16 MFMA)
    bgemm<0, 1><<<dim3(G_ / 128, 16), 256, 0, stream>>>(x_b, Wih1b, Xgb, G_, E_);       // Xg (bf16 out)
    bgemm<0, 0><<<dim3(E_ / 128, 16), 256, 0, stream>>>(x_b, Wib, Lacc, E_, E_);        // Xi -> Lacc
    bgemm<0, 0><<<dim3(H_ / 128, 32), 256, 0, stream>>>(ctxb, WkTb, cacheK, H_, C_);    // cacheK

    // persistent scan
    hipFuncSetAttribute((const void*)scan_kernel, hipFuncAttributeMaxDynamicSharedMemorySize, SMEM_BYTES);
    scan_kernel<<<NBLK, 256, SMEM_BYTES, stream>>>(
        Whh1b, Whh2b, WqTb, Wih2b, Xgb,
        b_ih1, b_hh1, b_ih2, b_hh2, bq, v_attn, cmask, hidden, cacheK, ctxb,
        qg, hf, hb, h1b, attnseq, outseq,
        (float*)d_out + (size_t)B_ * T_ * E_, bar);

    // epilogue GEMMs accumulate into Lacc
    bgemm<1, 0><<<dim3(E_ / 128, 16), 256, 0, stream>>>(outseq, Whb, Lacc, E_, H_);
    bgemm<1, 0><<<dim3(E_ / 128, 16), 256, 0, stream>>>(attnseq, Wcb, Lacc, E_, C_);

    final_kernel<<<(B_ * T_ * E_) / 256, 256, 0, stream>>>(Lacc, bi, bh, bc, (float*)d_out);
}

// Round 5
// 15438.083 us; speedup vs baseline: 2.3411x; 2.3411x over previous
//
#include <hip/hip_runtime.h>
#include <math.h>

#define B_ 64
#define T_ 32
#define S_ 64
#define E_ 512
#define H_ 1024
#define C_ 2048
#define G_ 3072
#define NBLK 256
#define FLSTR 16   // 16 uints = 64B padding per flag slot

typedef __bf16 bf16_t;
typedef bf16_t bf16x8 __attribute__((ext_vector_type(8)));
typedef float f32x4 __attribute__((ext_vector_type(4)));

__device__ __forceinline__ float sigm_(float x) { return 1.f / (1.f + __expf(-x)); }
__device__ __forceinline__ float tanh_(float x) { return 1.f - 2.f / (__expf(2.f * x) + 1.f); }

// split 8 consecutive f32 into hi/lo bf16x8
__device__ __forceinline__ void split8(const float* __restrict__ p, bf16x8& h, bf16x8& l)
{
    float4 a = *(const float4*)p;
    float4 b = *(const float4*)(p + 4);
    float v[8] = {a.x, a.y, a.z, a.w, b.x, b.y, b.z, b.w};
    #pragma unroll
    for (int q = 0; q < 8; ++q) {
        h[q] = (bf16_t)v[q];
        l[q] = (bf16_t)(v[q] - (float)h[q]);
    }
}

// ===================== helpers =====================
__global__ __launch_bounds__(256)
void embed_kernel(const int* __restrict__ y, const float* __restrict__ emb,
                  float* __restrict__ x)
{
    int i = blockIdx.x * 256 + threadIdx.x;      // B*T*E/4
    int row = i / (E_ / 4);
    int e4  = i % (E_ / 4);
    const float4* src = (const float4*)(emb + (size_t)y[row] * E_);
    ((float4*)(x + (size_t)row * E_))[e4] = src[e4];
}

__global__ void transpose_kernel(const float* __restrict__ in, float* __restrict__ out,
                                 int R, int Ccols)   // out[c][r] = in[r][c]
{
    __shared__ float t[32][33];
    int r0 = blockIdx.y * 32, c0 = blockIdx.x * 32;
    t[threadIdx.y][threadIdx.x] = in[(size_t)(r0 + threadIdx.y) * Ccols + c0 + threadIdx.x];
    __syncthreads();
    out[(size_t)(c0 + threadIdx.y) * R + r0 + threadIdx.x] = t[threadIdx.x][threadIdx.y];
}

__global__ __launch_bounds__(256)
void cvt_ctx(const float* __restrict__ in, bf16_t* __restrict__ out)
{
    int i = blockIdx.x * 256 + threadIdx.x;   // over 4096*2048/8
    const float4* s4 = (const float4*)in + 2 * i;
    float4 a = s4[0], b = s4[1];
    bf16x8 o;
    o[0] = (bf16_t)a.x; o[1] = (bf16_t)a.y; o[2] = (bf16_t)a.z; o[3] = (bf16_t)a.w;
    o[4] = (bf16_t)b.x; o[5] = (bf16_t)b.y; o[6] = (bf16_t)b.z; o[7] = (bf16_t)b.w;
    ((bf16x8*)out)[i] = o;
}

// ============ split-precision GEMM: f32 A[M,K] @ f32 Wt[N,K]^T -> f32 =======
// 128x128 tile, BK=32, 3-term bf16 MFMA (hi*hi + hi*lo + lo*hi) ~= f32.
#define LSTR 80

template<int ACCUM>
__global__ __launch_bounds__(256)
void sgemm(const float* __restrict__ A, const float* __restrict__ Wt,
           float* __restrict__ out, int N, int K)
{
    __shared__ char AH[128 * LSTR];
    __shared__ char AL[128 * LSTR];
    __shared__ char WH[128 * LSTR];
    __shared__ char WL[128 * LSTR];
    const int tid = threadIdx.x;
    const int lane = tid & 63, wave = tid >> 6;
    const int m0 = blockIdx.y * 128, n0 = blockIdx.x * 128;
    const int wm = (wave & 1) * 64, wn = (wave >> 1) * 64;
    const int l15 = lane & 15, l4 = lane >> 4;

    f32x4 acc[4][4] = {};

    for (int k0 = 0; k0 < K; k0 += 32) {
        #pragma unroll
        for (int p = 0; p < 2; ++p) {
            int e = tid + p * 256;           // 512 chunks of 8 f32 (128 rows x 4)
            int row = e >> 2, ch = e & 3;
            int off = row * LSTR + ch * 16;
            bf16x8 h, l;
            split8(A + (size_t)(m0 + row) * K + k0 + ch * 8, h, l);
            *(bf16x8*)(AH + off) = h; *(bf16x8*)(AL + off) = l;
            split8(Wt + (size_t)(n0 + row) * K + k0 + ch * 8, h, l);
            *(bf16x8*)(WH + off) = h; *(bf16x8*)(WL + off) = l;
        }
        __syncthreads();
        bf16x8 ah[4], al[4], wh[4], wl[4];
        #pragma unroll
        for (int i = 0; i < 4; ++i) {
            int off = (wm + i * 16 + l15) * LSTR + l4 * 16;
            ah[i] = *(const bf16x8*)(AH + off);
            al[i] = *(const bf16x8*)(AL + off);
        }
        #pragma unroll
        for (int j = 0; j < 4; ++j) {
            int off = (wn + j * 16 + l15) * LSTR + l4 * 16;
            wh[j] = *(const bf16x8*)(WH + off);
            wl[j] = *(const bf16x8*)(WL + off);
        }
        #pragma unroll
        for (int i = 0; i < 4; ++i)
            #pragma unroll
            for (int j = 0; j < 4; ++j) {
                acc[i][j] = __builtin_amdgcn_mfma_f32_16x16x32_bf16(ah[i], wh[j], acc[i][j], 0, 0, 0);
                acc[i][j] = __builtin_amdgcn_mfma_f32_16x16x32_bf16(ah[i], wl[j], acc[i][j], 0, 0, 0);
                acc[i][j] = __builtin_amdgcn_mfma_f32_16x16x32_bf16(al[i], wh[j], acc[i][j], 0, 0, 0);
            }
        __syncthreads();
    }

    #pragma unroll
    for (int i = 0; i < 4; ++i)
        #pragma unroll
        for (int j = 0; j < 4; ++j)
            #pragma unroll
            for (int r = 0; r < 4; ++r) {
                int m = m0 + wm + i * 16 + l4 * 4 + r;
                int n = n0 + wn + j * 16 + l15;
                if (ACCUM) out[(size_t)m * N + n] += acc[i][j][r];
                else       out[(size_t)m * N + n]  = acc[i][j][r];
            }
}

// ===================== persistent scan kernel =====================
// LDS layout (bytes), total exactly 160 KiB. 12-row tiles' phantom rows
// (l15=12..15 fragment reads) land in the *following* region: harmless
// finite garbage affecting only discarded output columns.
#define W1H_OFF 0         // W_hh1 hi : 12 rows x 2048B
#define W1L_OFF 24576     // W_hh1 lo : 12 rows
#define W3H_OFF 49152     // W_ih2 hi : 12 rows x 4096B (phantom -> W2H, cols 12-15 unused)
#define W2H_OFF 98304     // [W_hh2 gates; WqT] hi : 16 rows x 2048B
#define W2L_OFF 131072    // lo : 16 rows -> ends 163840
#define SMEM_BYTES 163840

__device__ __forceinline__ void gbar(unsigned* flags, unsigned* done,
                                     unsigned epoch, int blk, int tid)
{
    __threadfence();
    __syncthreads();
    if (blk == 0) {
        if (tid > 0) {
            while (__hip_atomic_load(&flags[tid * FLSTR], __ATOMIC_ACQUIRE,
                                     __HIP_MEMORY_SCOPE_AGENT) < epoch)
                __builtin_amdgcn_s_sleep(2);
        }
        __syncthreads();
        if (tid < 8)
            __hip_atomic_store(&done[tid * FLSTR], epoch, __ATOMIC_RELEASE,
                               __HIP_MEMORY_SCOPE_AGENT);
        __syncthreads();
    } else {
        if (tid == 0) {
            __hip_atomic_store(&flags[blk * FLSTR], epoch, __ATOMIC_RELEASE,
                               __HIP_MEMORY_SCOPE_AGENT);
            while (__hip_atomic_load(&done[(blk & 7) * FLSTR], __ATOMIC_ACQUIRE,
                                     __HIP_MEMORY_SCOPE_AGENT) < epoch)
                __builtin_amdgcn_s_sleep(2);
        }
        __syncthreads();
    }
    __threadfence();
}

__global__ __launch_bounds__(256, 1)
void scan_kernel(
    const float* __restrict__ Whh1, const float* __restrict__ Whh2,
    const float* __restrict__ WqT,  const float* __restrict__ Wih2,
    const float* __restrict__ Xg,
    const float* __restrict__ b_ih1, const float* __restrict__ b_hh1,
    const float* __restrict__ b_ih2, const float* __restrict__ b_hh2,
    const float* __restrict__ bq,    const float* __restrict__ v_attn,
    const int*   __restrict__ cmask,
    const float* __restrict__ hidden,
    const float* __restrict__ cacheK, const bf16_t* __restrict__ ctxb,
    float* __restrict__ qg, float* __restrict__ hf,
    bf16_t* __restrict__ hbH, bf16_t* __restrict__ hbL,
    bf16_t* __restrict__ h1H, bf16_t* __restrict__ h1L,
    bf16_t* __restrict__ atH, bf16_t* __restrict__ atL,
    float* __restrict__ attnseq, float* __restrict__ outseq,
    float* __restrict__ hfinal,
    float* __restrict__ scg, float* __restrict__ prg,
    unsigned* __restrict__ flags, unsigned* __restrict__ done)
{
    extern __shared__ char sm[];
    const int tid = threadIdx.x, blk = blockIdx.x;
    const int lane = tid & 63, wave = tid >> 6;
    const int l15 = lane & 15, l4 = lane >> 4;
    const int blk4 = blk * 4;

    // ---- stage weight slices into LDS as hi/lo bf16 (swizzled) ----
    for (int e = tid; e < 12 * 128; e += 256) {            // W_hh1 (K=1024)
        int r = e >> 7, c = e & 127;
        bf16x8 h, l;
        split8(Whh1 + (size_t)((r >> 2) * 1024 + blk4 + (r & 3)) * 1024 + c * 8, h, l);
        int off = r * 2048 + ((c * 16) ^ ((r & 7) << 4));
        *(bf16x8*)(sm + W1H_OFF + off) = h;
        *(bf16x8*)(sm + W1L_OFF + off) = l;
    }
    for (int e = tid; e < 16 * 128; e += 256) {            // [W_hh2 gates; WqT] (K=1024)
        int r = e >> 7, c = e & 127;
        const float* src = (r < 12)
            ? Whh2 + (size_t)((r >> 2) * 1024 + blk4 + (r & 3)) * 1024 + c * 8
            : WqT + (size_t)(blk4 + r - 12) * 1024 + c * 8;
        bf16x8 h, l;
        split8(src, h, l);
        int off = r * 2048 + ((c * 16) ^ ((r & 7) << 4));
        *(bf16x8*)(sm + W2H_OFF + off) = h;
        *(bf16x8*)(sm + W2L_OFF + off) = l;
    }
    for (int e = tid; e < 12 * 256; e += 256) {            // W_ih2 hi only (K=2048)
        int r = e >> 8, c = e & 255;
        bf16x8 h, l;
        split8(Wih2 + (size_t)((r >> 2) * 1024 + blk4 + (r & 3)) * 2048 + c * 8, h, l);
        *(bf16x8*)(sm + W3H_OFF + r * 4096 + ((c * 16) ^ ((r & 7) << 4))) = h;
    }

    {   // h init (each block owns 256 of the 65536 h-elements)
        int idx = blk * 256 + tid;
        float hv = hidden[idx];
        hf[idx] = hv;
        bf16_t hh = (bf16_t)hv;
        hbH[idx] = hh;
        hbL[idx] = (bf16_t)(hv - (float)hh);
    }

    // attention blocks: v_attn in registers
    float vreg[16];
    if (blk < 64) {
        #pragma unroll
        for (int i = 0; i < 16; ++i) vreg[i] = v_attn[lane + 64 * i];
    }

    // per-thread GRU biases (threads with l15 < 4 own hidden index j)
    const int j = blk4 + l15;
    float bi1r = 0, bi1z = 0, bi1n = 0, bh1r = 0, bh1z = 0, bh1n = 0;
    float bi2r = 0, bi2z = 0, bi2n = 0, bh2r = 0, bh2z = 0, bh2n = 0;
    if (l15 < 4) {
        bi1r = b_ih1[j]; bi1z = b_ih1[1024 + j]; bi1n = b_ih1[2048 + j];
        bh1r = b_hh1[j]; bh1z = b_hh1[1024 + j]; bh1n = b_hh1[2048 + j];
        bi2r = b_ih2[j]; bi2z = b_ih2[1024 + j]; bi2n = b_ih2[2048 + j];
        bh2r = b_hh2[j]; bh2z = b_hh2[1024 + j]; bh2n = b_hh2[2048 + j];
    }

    unsigned epoch = 0;
    gbar(flags, done, ++epoch, blk, tid);

    for (int t = 0; t < T_; ++t) {
        // ===== P0: gh1 = h @ W_hh1^T (split 3-term) + in-register GRU1 =====
        f32x4 acc0 = {0.f, 0.f, 0.f, 0.f};
        {
            const bf16_t* ah = hbH + (size_t)(wave * 16 + l15) * 1024;
            const bf16_t* al = hbL + (size_t)(wave * 16 + l15) * 1024;
            #pragma unroll 8
            for (int kk = 0; kk < 32; ++kk) {
                bf16x8 avh = *(const bf16x8*)(ah + kk * 32 + l4 * 8);
                bf16x8 avl = *(const bf16x8*)(al + kk * 32 + l4 * 8);
                int boff = (kk * 64 + l4 * 16) ^ ((l15 & 7) << 4);
                bf16x8 bvh = *(const bf16x8*)(sm + W1H_OFF + l15 * 2048 + boff);
                bf16x8 bvl = *(const bf16x8*)(sm + W1L_OFF + l15 * 2048 + boff);
                acc0 = __builtin_amdgcn_mfma_f32_16x16x32_bf16(avh, bvh, acc0, 0, 0, 0);
                acc0 = __builtin_amdgcn_mfma_f32_16x16x32_bf16(avl, bvh, acc0, 0, 0, 0);
                acc0 = __builtin_amdgcn_mfma_f32_16x16x32_bf16(avh, bvl, acc0, 0, 0, 0);
            }
        }
        float h1r_[4] = {0.f, 0.f, 0.f, 0.f};
        #pragma unroll
        for (int r2 = 0; r2 < 4; ++r2) {
            float gr = acc0[r2];
            float gz = __shfl(acc0[r2], (lane & 48) | (l15 + 4), 64);
            float gn = __shfl(acc0[r2], (lane & 48) | (l15 + 8), 64);
            if (l15 < 4) {
                int b = wave * 16 + l4 * 4 + r2;
                const float* xg = Xg + ((size_t)b * T_ + t) * 3072;
                float rr = sigm_(xg[j]          + bi1r + gr + bh1r);
                float zz = sigm_(xg[1024 + j]   + bi1z + gz + bh1z);
                float nn = tanh_(xg[2048 + j]   + bi1n + rr * (gn + bh1n));
                float h1v = (1.f - zz) * nn + zz * hf[b * 1024 + j];
                h1r_[r2] = h1v;
                bf16_t hh = (bf16_t)h1v;
                h1H[b * 1024 + j] = hh;
                h1L[b * 1024 + j] = (bf16_t)(h1v - (float)hh);
            }
        }
        gbar(flags, done, ++epoch, blk, tid);

        // ===== P1: [gh2 | q] = h1 @ [W_hh2 ; WqT]^T (split 3-term) =====
        f32x4 acc1 = {0.f, 0.f, 0.f, 0.f};
        {
            const bf16_t* ah = h1H + (size_t)(wave * 16 + l15) * 1024;
            const bf16_t* al = h1L + (size_t)(wave * 16 + l15) * 1024;
            #pragma unroll 8
            for (int kk = 0; kk < 32; ++kk) {
                bf16x8 avh = *(const bf16x8*)(ah + kk * 32 + l4 * 8);
                bf16x8 avl = *(const bf16x8*)(al + kk * 32 + l4 * 8);
                int boff = (kk * 64 + l4 * 16) ^ ((l15 & 7) << 4);
                bf16x8 bvh = *(const bf16x8*)(sm + W2H_OFF + l15 * 2048 + boff);
                bf16x8 bvl = *(const bf16x8*)(sm + W2L_OFF + l15 * 2048 + boff);
                acc1 = __builtin_amdgcn_mfma_f32_16x16x32_bf16(avh, bvh, acc1, 0, 0, 0);
                acc1 = __builtin_amdgcn_mfma_f32_16x16x32_bf16(avl, bvh, acc1, 0, 0, 0);
                acc1 = __builtin_amdgcn_mfma_f32_16x16x32_bf16(avh, bvl, acc1, 0, 0, 0);
            }
        }
        if (l15 >= 12) {
            int jq = blk4 + l15 - 12;
            #pragma unroll
            for (int r2 = 0; r2 < 4; ++r2)
                qg[(wave * 16 + l4 * 4 + r2) * 1024 + jq] = acc1[r2];
        }
        gbar(flags, done, ++epoch, blk, tid);

        // ===== P2: attention (blocks 0..63, one batch each) =====
        if (blk < 64) {
            const int b = blk;
            float qreg[16];
            #pragma unroll
            for (int i = 0; i < 16; ++i)
                qreg[i] = qg[b * 1024 + lane + 64 * i] + bq[lane + 64 * i];
            for (int s = wave; s < 64; s += 4) {
                const float* ck = cacheK + ((size_t)b * 64 + s) * 1024;
                float sum = 0.f;
                #pragma unroll
                for (int i = 0; i < 16; ++i)
                    sum += tanh_(qreg[i] + ck[lane + 64 * i]) * vreg[i];
                #pragma unroll
                for (int off = 32; off; off >>= 1) sum += __shfl_down(sum, off, 64);
                if (lane == 0) scg[b * 64 + s] = sum;
            }
            __syncthreads();
            if (wave == 0) {
                float v = (cmask[b * 64 + lane] != 0) ? -3.4e38f : scg[b * 64 + lane];
                float mx = v;
                #pragma unroll
                for (int off = 32; off; off >>= 1) mx = fmaxf(mx, __shfl_xor(mx, off, 64));
                float e = __expf(v - mx);
                float sden = e;
                #pragma unroll
                for (int off = 32; off; off >>= 1) sden += __shfl_xor(sden, off, 64);
                prg[b * 64 + lane] = e / sden;
            }
            __syncthreads();
            float prv = prg[b * 64 + lane];
            #pragma unroll
            for (int i = 0; i < 8; ++i) {
                int c = tid + 256 * i;
                const bf16_t* cb = ctxb + (size_t)b * 64 * 2048 + c;
                float sum = 0.f;
                #pragma unroll 8
                for (int s = 0; s < 64; ++s)
                    sum += __shfl(prv, s, 64) * (float)cb[(size_t)s * 2048];
                attnseq[((size_t)b * T_ + t) * 2048 + c] = sum;
                bf16_t hh = (bf16_t)sum;
                atH[b * 2048 + c] = hh;
                atL[b * 2048 + c] = (bf16_t)(sum - (float)hh);
            }
        }
        gbar(flags, done, ++epoch, blk, tid);

        // ===== P3: gi2 = attn @ W_ih2^T (A split, W hi) + GRU2 =====
        f32x4 acc3 = {0.f, 0.f, 0.f, 0.f};
        {
            const bf16_t* ah = atH + (size_t)(wave * 16 + l15) * 2048;
            const bf16_t* al = atL + (size_t)(wave * 16 + l15) * 2048;
            #pragma unroll 8
            for (int kk = 0; kk < 64; ++kk) {
                bf16x8 avh = *(const bf16x8*)(ah + kk * 32 + l4 * 8);
                bf16x8 avl = *(const bf16x8*)(al + kk * 32 + l4 * 8);
                bf16x8 bvh = *(const bf16x8*)(sm + W3H_OFF + l15 * 4096 +
                                              ((kk * 64 + l4 * 16) ^ ((l15 & 7) << 4)));
                acc3 = __builtin_amdgcn_mfma_f32_16x16x32_bf16(avh, bvh, acc3, 0, 0, 0);
                acc3 = __builtin_amdgcn_mfma_f32_16x16x32_bf16(avl, bvh, acc3, 0, 0, 0);
            }
        }
        #pragma unroll
        for (int r2 = 0; r2 < 4; ++r2) {
            float ir  = acc3[r2];
            float iz  = __shfl(acc3[r2], (lane & 48) | (l15 + 4), 64);
            float in2 = __shfl(acc3[r2], (lane & 48) | (l15 + 8), 64);
            float hr  = acc1[r2];
            float hz  = __shfl(acc1[r2], (lane & 48) | (l15 + 4), 64);
            float hn  = __shfl(acc1[r2], (lane & 48) | (l15 + 8), 64);
            if (l15 < 4) {
                int b = wave * 16 + l4 * 4 + r2;
                float rr = sigm_(ir + bi2r + hr + bh2r);
                float zz = sigm_(iz + bi2z + hz + bh2z);
                float nn = tanh_(in2 + bi2n + rr * (hn + bh2n));
                float h2 = (1.f - zz) * nn + zz * h1r_[r2];
                hf[b * 1024 + j] = h2;
                bf16_t hh = (bf16_t)h2;
                hbH[b * 1024 + j] = hh;
                hbL[b * 1024 + j] = (bf16_t)(h2 - (float)hh);
                outseq[((size_t)b * T_ + t) * 1024 + j] = h2;
                if (t == T_ - 1) hfinal[b * 1024 + j] = h2;
            }
        }
        gbar(flags, done, ++epoch, blk, tid);
    }
}

// ===================== final logits =====================
__global__ __launch_bounds__(256)
void final_kernel(const float* __restrict__ Lacc,
                  const float* __restrict__ bi, const float* __restrict__ bh,
                  const float* __restrict__ bc, float* __restrict__ out)
{
    int i = blockIdx.x * 256 + threadIdx.x;
    int e = i & 511;
    out[i] = tanh_(Lacc[i] + bi[e] + bh[e] + bc[e]);
}

// ===================== host =====================
extern "C" void kernel_launch(void* const* d_in, const int* in_sizes, int n_in,
                              void* d_out, int out_size, void* d_ws, size_t ws_size,
                              hipStream_t stream)
{
    const int*   y       = (const int*)  d_in[0];
    const float* context = (const float*)d_in[1];
    const int*   cmask   = (const int*)  d_in[2];
    const float* hidden  = (const float*)d_in[3];
    const float* emb     = (const float*)d_in[4];
    const float* W_ih1   = (const float*)d_in[5];
    const float* W_hh1   = (const float*)d_in[6];
    const float* b_ih1   = (const float*)d_in[7];
    const float* b_hh1   = (const float*)d_in[8];
    const float* Wq      = (const float*)d_in[9];
    const float* bq      = (const float*)d_in[10];
    const float* Wk      = (const float*)d_in[11];
    const float* v_attn  = (const float*)d_in[12];
    const float* W_ih2   = (const float*)d_in[13];
    const float* W_hh2   = (const float*)d_in[14];
    const float* b_ih2   = (const float*)d_in[15];
    const float* b_hh2   = (const float*)d_in[16];
    const float* Wi      = (const float*)d_in[17];
    const float* bi      = (const float*)d_in[18];
    const float* Wh      = (const float*)d_in[19];
    const float* bh      = (const float*)d_in[20];
    const float* Wc      = (const float*)d_in[21];
    const float* bc      = (const float*)d_in[22];

    char* ws = (char*)d_ws;
    size_t o = 0;
    auto alloc = [&](size_t bytes) { char* p = ws + o; o += (bytes + 255) & ~(size_t)255; return p; };
    unsigned* flags = (unsigned*)alloc(NBLK * FLSTR * 4);   // 16 KB
    unsigned* done  = (unsigned*)alloc(8 * FLSTR * 4);      // 512 B (contiguous w/ flags)
    float*  x       = (float*) alloc((size_t)2048 * 512 * 4);
    float*  WkT     = (float*) alloc((size_t)1024 * 2048 * 4);
    float*  WqT     = (float*) alloc((size_t)1024 * 1024 * 4);
    bf16_t* ctxb    = (bf16_t*)alloc((size_t)4096 * 2048 * 2);
    float*  Xg      = (float*) alloc((size_t)2048 * 3072 * 4);
    float*  Lacc    = (float*) alloc((size_t)2048 * 512 * 4);
    float*  cacheK  = (float*) alloc((size_t)4096 * 1024 * 4);
    float*  qg      = (float*) alloc((size_t)64 * 1024 * 4);
    float*  hf      = (float*) alloc((size_t)64 * 1024 * 4);
    bf16_t* hbH     = (bf16_t*)alloc((size_t)64 * 1024 * 2);
    bf16_t* hbL     = (bf16_t*)alloc((size_t)64 * 1024 * 2);
    bf16_t* h1H     = (bf16_t*)alloc((size_t)64 * 1024 * 2);
    bf16_t* h1L     = (bf16_t*)alloc((size_t)64 * 1024 * 2);
    bf16_t* atH     = (bf16_t*)alloc((size_t)64 * 2048 * 2);
    bf16_t* atL     = (bf16_t*)alloc((size_t)64 * 2048 * 2);
    float*  attnseq = (float*) alloc((size_t)2048 * 2048 * 4);
    float*  outseq  = (float*) alloc((size_t)2048 * 1024 * 4);
    float*  scg     = (float*) alloc((size_t)64 * 64 * 4);
    float*  prg     = (float*) alloc((size_t)64 * 64 * 4);

    hipMemsetAsync(flags, 0, (NBLK * FLSTR + 8 * FLSTR) * 4, stream);

    embed_kernel<<<(B_*T_*E_/4 + 255)/256, 256, 0, stream>>>(y, emb, x);
    transpose_kernel<<<dim3(1024/32, 2048/32), dim3(32,32), 0, stream>>>(Wk, WkT, 2048, 1024);
    transpose_kernel<<<dim3(1024/32, 1024/32), dim3(32,32), 0, stream>>>(Wq, WqT, 1024, 1024);
    cvt_ctx<<<(4096*2048/8)/256, 256, 0, stream>>>(context, ctxb);

    // prologue GEMMs (split-precision MFMA, f32 in/out)
    sgemm<0><<<dim3(G_/128, 16), 256, 0, stream>>>(x, W_ih1, Xg, G_, E_);
    sgemm<0><<<dim3(E_/128, 16), 256, 0, stream>>>(x, Wi, Lacc, E_, E_);
    sgemm<0><<<dim3(H_/128, 32), 256, 0, stream>>>(context, WkT, cacheK, H_, C_);

    // persistent scan
    hipFuncSetAttribute((const void*)scan_kernel, hipFuncAttributeMaxDynamicSharedMemorySize, SMEM_BYTES);
    scan_kernel<<<NBLK, 256, SMEM_BYTES, stream>>>(
        W_hh1, W_hh2, WqT, W_ih2, Xg,
        b_ih1, b_hh1, b_ih2, b_hh2, bq, v_attn, cmask, hidden, cacheK, ctxb,
        qg, hf, hbH, hbL, h1H, h1L, atH, atL, attnseq, outseq,
        (float*)d_out + (size_t)B_ * T_ * E_, scg, prg, flags, done);

    // epilogue GEMMs accumulate into Lacc
    sgemm<1><<<dim3(E_/128, 16), 256, 0, stream>>>(outseq, Wh, Lacc, E_, H_);
    sgemm<1><<<dim3(E_/128, 16), 256, 0, stream>>>(attnseq, Wc, Lacc, E_, C_);

    final_kernel<<<(B_*T_*E_)/256, 256, 0, stream>>>(Lacc, bi, bh, bc, (float*)d_out);
}

// Round 6
// 4993.309 us; speedup vs baseline: 7.2381x; 3.0918x over previous
//
#include <hip/hip_runtime.h>
#include <math.h>

#define B_ 64
#define T_ 32
#define S_ 64
#define E_ 512
#define H_ 1024
#define C_ 2048
#define G_ 3072
#define NBLK 256
#define FLSTR 16   // 16 uints = 64B padding per flag slot

typedef __bf16 bf16_t;
typedef bf16_t bf16x8 __attribute__((ext_vector_type(8)));
typedef float f32x4 __attribute__((ext_vector_type(4)));

__device__ __forceinline__ float sigm_(float x) { return 1.f / (1.f + __expf(-x)); }
__device__ __forceinline__ float tanh_(float x) { return 1.f - 2.f / (__expf(2.f * x) + 1.f); }

// split 8 consecutive f32 into hi/lo bf16x8
__device__ __forceinline__ void split8(const float* __restrict__ p, bf16x8& h, bf16x8& l)
{
    float4 a = *(const float4*)p;
    float4 b = *(const float4*)(p + 4);
    float v[8] = {a.x, a.y, a.z, a.w, b.x, b.y, b.z, b.w};
    #pragma unroll
    for (int q = 0; q < 8; ++q) {
        h[q] = (bf16_t)v[q];
        l[q] = (bf16_t)(v[q] - (float)h[q]);
    }
}

// ===================== helpers =====================
__global__ __launch_bounds__(256)
void embed_kernel(const int* __restrict__ y, const float* __restrict__ emb,
                  float* __restrict__ x)
{
    int i = blockIdx.x * 256 + threadIdx.x;      // B*T*E/4
    int row = i / (E_ / 4);
    int e4  = i % (E_ / 4);
    const float4* src = (const float4*)(emb + (size_t)y[row] * E_);
    ((float4*)(x + (size_t)row * E_))[e4] = src[e4];
}

__global__ void transpose_kernel(const float* __restrict__ in, float* __restrict__ out,
                                 int R, int Ccols)   // out[c][r] = in[r][c]
{
    __shared__ float t[32][33];
    int r0 = blockIdx.y * 32, c0 = blockIdx.x * 32;
    t[threadIdx.y][threadIdx.x] = in[(size_t)(r0 + threadIdx.y) * Ccols + c0 + threadIdx.x];
    __syncthreads();
    out[(size_t)(c0 + threadIdx.y) * R + r0 + threadIdx.x] = t[threadIdx.x][threadIdx.y];
}

__global__ __launch_bounds__(256)
void cvt_ctx(const float* __restrict__ in, bf16_t* __restrict__ out)
{
    int i = blockIdx.x * 256 + threadIdx.x;   // over 4096*2048/8
    const float4* s4 = (const float4*)in + 2 * i;
    float4 a = s4[0], b = s4[1];
    bf16x8 o;
    o[0] = (bf16_t)a.x; o[1] = (bf16_t)a.y; o[2] = (bf16_t)a.z; o[3] = (bf16_t)a.w;
    o[4] = (bf16_t)b.x; o[5] = (bf16_t)b.y; o[6] = (bf16_t)b.z; o[7] = (bf16_t)b.w;
    ((bf16x8*)out)[i] = o;
}

// ============ split-precision GEMM: f32 A[M,K] @ f32 Wt[N,K]^T -> f32 =======
#define LSTR 80

template<int ACCUM>
__global__ __launch_bounds__(256)
void sgemm(const float* __restrict__ A, const float* __restrict__ Wt,
           float* __restrict__ out, int N, int K)
{
    __shared__ char AH[128 * LSTR];
    __shared__ char AL[128 * LSTR];
    __shared__ char WH[128 * LSTR];
    __shared__ char WL[128 * LSTR];
    const int tid = threadIdx.x;
    const int lane = tid & 63, wave = tid >> 6;
    const int m0 = blockIdx.y * 128, n0 = blockIdx.x * 128;
    const int wm = (wave & 1) * 64, wn = (wave >> 1) * 64;
    const int l15 = lane & 15, l4 = lane >> 4;

    f32x4 acc[4][4] = {};

    for (int k0 = 0; k0 < K; k0 += 32) {
        #pragma unroll
        for (int p = 0; p < 2; ++p) {
            int e = tid + p * 256;
            int row = e >> 2, ch = e & 3;
            int off = row * LSTR + ch * 16;
            bf16x8 h, l;
            split8(A + (size_t)(m0 + row) * K + k0 + ch * 8, h, l);
            *(bf16x8*)(AH + off) = h; *(bf16x8*)(AL + off) = l;
            split8(Wt + (size_t)(n0 + row) * K + k0 + ch * 8, h, l);
            *(bf16x8*)(WH + off) = h; *(bf16x8*)(WL + off) = l;
        }
        __syncthreads();
        bf16x8 ah[4], al[4], wh[4], wl[4];
        #pragma unroll
        for (int i = 0; i < 4; ++i) {
            int off = (wm + i * 16 + l15) * LSTR + l4 * 16;
            ah[i] = *(const bf16x8*)(AH + off);
            al[i] = *(const bf16x8*)(AL + off);
        }
        #pragma unroll
        for (int j = 0; j < 4; ++j) {
            int off = (wn + j * 16 + l15) * LSTR + l4 * 16;
            wh[j] = *(const bf16x8*)(WH + off);
            wl[j] = *(const bf16x8*)(WL + off);
        }
        #pragma unroll
        for (int i = 0; i < 4; ++i)
            #pragma unroll
            for (int j = 0; j < 4; ++j) {
                acc[i][j] = __builtin_amdgcn_mfma_f32_16x16x32_bf16(ah[i], wh[j], acc[i][j], 0, 0, 0);
                acc[i][j] = __builtin_amdgcn_mfma_f32_16x16x32_bf16(ah[i], wl[j], acc[i][j], 0, 0, 0);
                acc[i][j] = __builtin_amdgcn_mfma_f32_16x16x32_bf16(al[i], wh[j], acc[i][j], 0, 0, 0);
            }
        __syncthreads();
    }

    #pragma unroll
    for (int i = 0; i < 4; ++i)
        #pragma unroll
        for (int j = 0; j < 4; ++j)
            #pragma unroll
            for (int r = 0; r < 4; ++r) {
                int m = m0 + wm + i * 16 + l4 * 4 + r;
                int n = n0 + wn + j * 16 + l15;
                if (ACCUM) out[(size_t)m * N + n] += acc[i][j][r];
                else       out[(size_t)m * N + n]  = acc[i][j][r];
            }
}

// ===================== persistent scan kernel =====================
#define W1H_OFF 0         // W_hh1 hi : 12 rows x 2048B
#define W1L_OFF 24576     // W_hh1 lo : 12 rows
#define W3H_OFF 49152     // W_ih2 hi : 12 rows x 4096B
#define W2H_OFF 98304     // [W_hh2 gates; WqT] hi : 16 rows x 2048B
#define W2L_OFF 131072    // lo : 16 rows -> ends 163840
#define SMEM_BYTES 163840

// Contention-free barrier with RELAXED polls (no per-iteration L2 invalidate).
// Exactly one release fence before signaling and one acquire fence after the
// poll exits, per block per barrier.
__device__ __forceinline__ void gbar(unsigned* flags, unsigned* done,
                                     unsigned epoch, int blk, int tid)
{
    __syncthreads();
    if (blk == 0) {
        if (tid == 0) __builtin_amdgcn_fence(__ATOMIC_RELEASE, "agent");
        if (tid > 0 && tid < NBLK) {
            while (__hip_atomic_load(&flags[tid * FLSTR], __ATOMIC_RELAXED,
                                     __HIP_MEMORY_SCOPE_AGENT) < epoch)
                __builtin_amdgcn_s_sleep(4);
        }
        __syncthreads();
        if (tid < 8)
            __hip_atomic_store(&done[tid * FLSTR], epoch, __ATOMIC_RELAXED,
                               __HIP_MEMORY_SCOPE_AGENT);
        if (tid == 0) __builtin_amdgcn_fence(__ATOMIC_ACQUIRE, "agent");
        __syncthreads();
    } else {
        if (tid == 0) {
            __builtin_amdgcn_fence(__ATOMIC_RELEASE, "agent");
            __hip_atomic_store(&flags[blk * FLSTR], epoch, __ATOMIC_RELAXED,
                               __HIP_MEMORY_SCOPE_AGENT);
            while (__hip_atomic_load(&done[(blk & 7) * FLSTR], __ATOMIC_RELAXED,
                                     __HIP_MEMORY_SCOPE_AGENT) < epoch)
                __builtin_amdgcn_s_sleep(4);
            __builtin_amdgcn_fence(__ATOMIC_ACQUIRE, "agent");
        }
        __syncthreads();
    }
}

__global__ __launch_bounds__(1024, 1)
void scan_kernel(
    const float* __restrict__ Whh1, const float* __restrict__ Whh2,
    const float* __restrict__ WqT,  const float* __restrict__ Wih2,
    const float* __restrict__ Xg,
    const float* __restrict__ b_ih1, const float* __restrict__ b_hh1,
    const float* __restrict__ b_ih2, const float* __restrict__ b_hh2,
    const float* __restrict__ bq,    const float* __restrict__ v_attn,
    const int*   __restrict__ cmask,
    const float* __restrict__ hidden,
    const float* __restrict__ cacheK, const bf16_t* __restrict__ ctxb,
    float* __restrict__ qg, float* __restrict__ hf,
    bf16_t* __restrict__ hbH, bf16_t* __restrict__ hbL,
    bf16_t* __restrict__ h1H, bf16_t* __restrict__ h1L,
    bf16_t* __restrict__ atH, bf16_t* __restrict__ atL,
    float* __restrict__ attnseq, float* __restrict__ outseq,
    float* __restrict__ hfinal,
    float* __restrict__ scg,
    unsigned* __restrict__ flags, unsigned* __restrict__ done)
{
    extern __shared__ char sm[];
    const int tid = threadIdx.x, blk = blockIdx.x;
    const int lane = tid & 63, wave = tid >> 6;   // 16 waves
    const int l15 = lane & 15, l4 = lane >> 4;
    const int blk4 = blk * 4;

    // ---- stage weight slices into LDS as hi/lo bf16 (swizzled) ----
    for (int e = tid; e < 12 * 128; e += 1024) {           // W_hh1 (K=1024)
        int r = e >> 7, c = e & 127;
        bf16x8 h, l;
        split8(Whh1 + (size_t)((r >> 2) * 1024 + blk4 + (r & 3)) * 1024 + c * 8, h, l);
        int off = r * 2048 + ((c * 16) ^ ((r & 7) << 4));
        *(bf16x8*)(sm + W1H_OFF + off) = h;
        *(bf16x8*)(sm + W1L_OFF + off) = l;
    }
    for (int e = tid; e < 16 * 128; e += 1024) {           // [W_hh2 gates; WqT] (K=1024)
        int r = e >> 7, c = e & 127;
        const float* src = (r < 12)
            ? Whh2 + (size_t)((r >> 2) * 1024 + blk4 + (r & 3)) * 1024 + c * 8
            : WqT + (size_t)(blk4 + r - 12) * 1024 + c * 8;
        bf16x8 h, l;
        split8(src, h, l);
        int off = r * 2048 + ((c * 16) ^ ((r & 7) << 4));
        *(bf16x8*)(sm + W2H_OFF + off) = h;
        *(bf16x8*)(sm + W2L_OFF + off) = l;
    }
    for (int e = tid; e < 12 * 256; e += 1024) {           // W_ih2 hi only (K=2048)
        int r = e >> 8, c = e & 255;
        bf16x8 h, l;
        split8(Wih2 + (size_t)((r >> 2) * 1024 + blk4 + (r & 3)) * 2048 + c * 8, h, l);
        *(bf16x8*)(sm + W3H_OFF + r * 4096 + ((c * 16) ^ ((r & 7) << 4))) = h;
    }

    if (tid < 256) {   // h init (each block owns 256 of the 65536 h-elements)
        int idx = blk * 256 + tid;
        float hv = hidden[idx];
        hf[idx] = hv;
        bf16_t hh = (bf16_t)hv;
        hbH[idx] = hh;
        hbL[idx] = (bf16_t)(hv - (float)hh);
    }

    // attention blocks: v_attn and bq in registers (time-invariant)
    float vreg[16], bqreg[16];
    if (blk < 64) {
        #pragma unroll
        for (int i = 0; i < 16; ++i) {
            vreg[i]  = v_attn[lane + 64 * i];
            bqreg[i] = bq[lane + 64 * i];
        }
    }

    // per-thread GRU biases (MFMA waves, threads with l15 < 4 own hidden index j)
    const int j = blk4 + l15;
    float bi1r = 0, bi1z = 0, bi1n = 0, bh1r = 0, bh1z = 0, bh1n = 0;
    float bi2r = 0, bi2z = 0, bi2n = 0, bh2r = 0, bh2z = 0, bh2n = 0;
    if (wave < 4 && l15 < 4) {
        bi1r = b_ih1[j]; bi1z = b_ih1[1024 + j]; bi1n = b_ih1[2048 + j];
        bh1r = b_hh1[j]; bh1z = b_hh1[1024 + j]; bh1n = b_hh1[2048 + j];
        bi2r = b_ih2[j]; bi2z = b_ih2[1024 + j]; bi2n = b_ih2[2048 + j];
        bh2r = b_hh2[j]; bh2z = b_hh2[1024 + j]; bh2n = b_hh2[2048 + j];
    }

    unsigned epoch = 0;
    gbar(flags, done, ++epoch, blk, tid);

    float h1r_[4] = {0.f, 0.f, 0.f, 0.f};
    f32x4 acc1 = {0.f, 0.f, 0.f, 0.f};

    for (int t = 0; t < T_; ++t) {
        // ===== P0: gh1 = h @ W_hh1^T (split 3-term) + in-register GRU1 =====
        if (wave < 4) {
            f32x4 acc0 = {0.f, 0.f, 0.f, 0.f};
            const bf16_t* ah = hbH + (size_t)(wave * 16 + l15) * 1024;
            const bf16_t* al = hbL + (size_t)(wave * 16 + l15) * 1024;
            #pragma unroll 8
            for (int kk = 0; kk < 32; ++kk) {
                bf16x8 avh = *(const bf16x8*)(ah + kk * 32 + l4 * 8);
                bf16x8 avl = *(const bf16x8*)(al + kk * 32 + l4 * 8);
                int boff = (kk * 64 + l4 * 16) ^ ((l15 & 7) << 4);
                bf16x8 bvh = *(const bf16x8*)(sm + W1H_OFF + l15 * 2048 + boff);
                bf16x8 bvl = *(const bf16x8*)(sm + W1L_OFF + l15 * 2048 + boff);
                acc0 = __builtin_amdgcn_mfma_f32_16x16x32_bf16(avh, bvh, acc0, 0, 0, 0);
                acc0 = __builtin_amdgcn_mfma_f32_16x16x32_bf16(avl, bvh, acc0, 0, 0, 0);
                acc0 = __builtin_amdgcn_mfma_f32_16x16x32_bf16(avh, bvl, acc0, 0, 0, 0);
            }
            #pragma unroll
            for (int r2 = 0; r2 < 4; ++r2) {
                float gr = acc0[r2];
                float gz = __shfl(acc0[r2], (lane & 48) | (l15 + 4), 64);
                float gn = __shfl(acc0[r2], (lane & 48) | (l15 + 8), 64);
                if (l15 < 4) {
                    int b = wave * 16 + l4 * 4 + r2;
                    const float* xg = Xg + ((size_t)b * T_ + t) * 3072;
                    float rr = sigm_(xg[j]          + bi1r + gr + bh1r);
                    float zz = sigm_(xg[1024 + j]   + bi1z + gz + bh1z);
                    float nn = tanh_(xg[2048 + j]   + bi1n + rr * (gn + bh1n));
                    float h1v = (1.f - zz) * nn + zz * hf[b * 1024 + j];
                    h1r_[r2] = h1v;
                    bf16_t hh = (bf16_t)h1v;
                    h1H[b * 1024 + j] = hh;
                    h1L[b * 1024 + j] = (bf16_t)(h1v - (float)hh);
                }
            }
        }
        gbar(flags, done, ++epoch, blk, tid);

        // ===== P1: [gh2 | q] = h1 @ [W_hh2 ; WqT]^T (split 3-term) =====
        if (wave < 4) {
            acc1 = (f32x4){0.f, 0.f, 0.f, 0.f};
            const bf16_t* ah = h1H + (size_t)(wave * 16 + l15) * 1024;
            const bf16_t* al = h1L + (size_t)(wave * 16 + l15) * 1024;
            #pragma unroll 8
            for (int kk = 0; kk < 32; ++kk) {
                bf16x8 avh = *(const bf16x8*)(ah + kk * 32 + l4 * 8);
                bf16x8 avl = *(const bf16x8*)(al + kk * 32 + l4 * 8);
                int boff = (kk * 64 + l4 * 16) ^ ((l15 & 7) << 4);
                bf16x8 bvh = *(const bf16x8*)(sm + W2H_OFF + l15 * 2048 + boff);
                bf16x8 bvl = *(const bf16x8*)(sm + W2L_OFF + l15 * 2048 + boff);
                acc1 = __builtin_amdgcn_mfma_f32_16x16x32_bf16(avh, bvh, acc1, 0, 0, 0);
                acc1 = __builtin_amdgcn_mfma_f32_16x16x32_bf16(avl, bvh, acc1, 0, 0, 0);
                acc1 = __builtin_amdgcn_mfma_f32_16x16x32_bf16(avh, bvl, acc1, 0, 0, 0);
            }
            if (l15 >= 12) {
                int jq = blk4 + l15 - 12;
                #pragma unroll
                for (int r2 = 0; r2 < 4; ++r2)
                    qg[(wave * 16 + l4 * 4 + r2) * 1024 + jq] = acc1[r2];
            }
        }
        gbar(flags, done, ++epoch, blk, tid);

        // ===== P2: attention (blocks 0..63, 16 waves each) =====
        if (blk < 64) {
            const int b = blk;
            float qreg[16];
            #pragma unroll
            for (int i = 0; i < 16; ++i)
                qreg[i] = qg[b * 1024 + lane + 64 * i] + bqreg[i];
            #pragma unroll
            for (int sl = 0; sl < 4; ++sl) {
                int s = wave * 4 + sl;
                const float* ck = cacheK + ((size_t)b * 64 + s) * 1024;
                float sum = 0.f;
                #pragma unroll
                for (int i = 0; i < 16; ++i)
                    sum += tanh_(qreg[i] + ck[lane + 64 * i]) * vreg[i];
                #pragma unroll
                for (int off = 32; off; off >>= 1) sum += __shfl_down(sum, off, 64);
                if (lane == 0) scg[b * 64 + s] = sum;
            }
            __syncthreads();
            // softmax (each wave redundantly; lane holds s=lane)
            float v = (cmask[b * 64 + lane] != 0) ? -3.4e38f : scg[b * 64 + lane];
            float mx = v;
            #pragma unroll
            for (int off = 32; off; off >>= 1) mx = fmaxf(mx, __shfl_xor(mx, off, 64));
            float e = __expf(v - mx);
            float sden = e;
            #pragma unroll
            for (int off = 32; off; off >>= 1) sden += __shfl_xor(sden, off, 64);
            float prv = e / sden;
            // PV: 2048 cols over 1024 threads (2 each)
            #pragma unroll
            for (int ci = 0; ci < 2; ++ci) {
                int c = tid + 1024 * ci;
                const bf16_t* cb = ctxb + (size_t)b * 64 * 2048 + c;
                float sum = 0.f;
                #pragma unroll 8
                for (int s = 0; s < 64; ++s)
                    sum += __shfl(prv, s, 64) * (float)cb[(size_t)s * 2048];
                attnseq[((size_t)b * T_ + t) * 2048 + c] = sum;
                bf16_t hh = (bf16_t)sum;
                atH[b * 2048 + c] = hh;
                atL[b * 2048 + c] = (bf16_t)(sum - (float)hh);
            }
        }
        gbar(flags, done, ++epoch, blk, tid);

        // ===== P3: gi2 = attn @ W_ih2^T (A split, W hi) + GRU2 =====
        if (wave < 4) {
            f32x4 acc3 = {0.f, 0.f, 0.f, 0.f};
            const bf16_t* ah = atH + (size_t)(wave * 16 + l15) * 2048;
            const bf16_t* al = atL + (size_t)(wave * 16 + l15) * 2048;
            #pragma unroll 8
            for (int kk = 0; kk < 64; ++kk) {
                bf16x8 avh = *(const bf16x8*)(ah + kk * 32 + l4 * 8);
                bf16x8 avl = *(const bf16x8*)(al + kk * 32 + l4 * 8);
                bf16x8 bvh = *(const bf16x8*)(sm + W3H_OFF + l15 * 4096 +
                                              ((kk * 64 + l4 * 16) ^ ((l15 & 7) << 4)));
                acc3 = __builtin_amdgcn_mfma_f32_16x16x32_bf16(avh, bvh, acc3, 0, 0, 0);
                acc3 = __builtin_amdgcn_mfma_f32_16x16x32_bf16(avl, bvh, acc3, 0, 0, 0);
            }
            #pragma unroll
            for (int r2 = 0; r2 < 4; ++r2) {
                float ir  = acc3[r2];
                float iz  = __shfl(acc3[r2], (lane & 48) | (l15 + 4), 64);
                float in2 = __shfl(acc3[r2], (lane & 48) | (l15 + 8), 64);
                float hr  = acc1[r2];
                float hz  = __shfl(acc1[r2], (lane & 48) | (l15 + 4), 64);
                float hn  = __shfl(acc1[r2], (lane & 48) | (l15 + 8), 64);
                if (l15 < 4) {
                    int b = wave * 16 + l4 * 4 + r2;
                    float rr = sigm_(ir + bi2r + hr + bh2r);
                    float zz = sigm_(iz + bi2z + hz + bh2z);
                    float nn = tanh_(in2 + bi2n + rr * (hn + bh2n));
                    float h2 = (1.f - zz) * nn + zz * h1r_[r2];
                    hf[b * 1024 + j] = h2;
                    bf16_t hh = (bf16_t)h2;
                    hbH[b * 1024 + j] = hh;
                    hbL[b * 1024 + j] = (bf16_t)(h2 - (float)hh);
                    outseq[((size_t)b * T_ + t) * 1024 + j] = h2;
                    if (t == T_ - 1) hfinal[b * 1024 + j] = h2;
                }
            }
        }
        gbar(flags, done, ++epoch, blk, tid);
    }
}

// ===================== final logits =====================
__global__ __launch_bounds__(256)
void final_kernel(const float* __restrict__ Lacc,
                  const float* __restrict__ bi, const float* __restrict__ bh,
                  const float* __restrict__ bc, float* __restrict__ out)
{
    int i = blockIdx.x * 256 + threadIdx.x;
    int e = i & 511;
    out[i] = tanh_(Lacc[i] + bi[e] + bh[e] + bc[e]);
}

// ===================== host =====================
extern "C" void kernel_launch(void* const* d_in, const int* in_sizes, int n_in,
                              void* d_out, int out_size, void* d_ws, size_t ws_size,
                              hipStream_t stream)
{
    const int*   y       = (const int*)  d_in[0];
    const float* context = (const float*)d_in[1];
    const int*   cmask   = (const int*)  d_in[2];
    const float* hidden  = (const float*)d_in[3];
    const float* emb     = (const float*)d_in[4];
    const float* W_ih1   = (const float*)d_in[5];
    const float* W_hh1   = (const float*)d_in[6];
    const float* b_ih1   = (const float*)d_in[7];
    const float* b_hh1   = (const float*)d_in[8];
    const float* Wq      = (const float*)d_in[9];
    const float* bq      = (const float*)d_in[10];
    const float* Wk      = (const float*)d_in[11];
    const float* v_attn  = (const float*)d_in[12];
    const float* W_ih2   = (const float*)d_in[13];
    const float* W_hh2   = (const float*)d_in[14];
    const float* b_ih2   = (const float*)d_in[15];
    const float* b_hh2   = (const float*)d_in[16];
    const float* Wi      = (const float*)d_in[17];
    const float* bi      = (const float*)d_in[18];
    const float* Wh      = (const float*)d_in[19];
    const float* bh      = (const float*)d_in[20];
    const float* Wc      = (const float*)d_in[21];
    const float* bc      = (const float*)d_in[22];

    char* ws = (char*)d_ws;
    size_t o = 0;
    auto alloc = [&](size_t bytes) { char* p = ws + o; o += (bytes + 255) & ~(size_t)255; return p; };
    unsigned* flags = (unsigned*)alloc(NBLK * FLSTR * 4);   // 16 KB
    unsigned* done  = (unsigned*)alloc(8 * FLSTR * 4);      // 512 B
    float*  x       = (float*) alloc((size_t)2048 * 512 * 4);
    float*  WkT     = (float*) alloc((size_t)1024 * 2048 * 4);
    float*  WqT     = (float*) alloc((size_t)1024 * 1024 * 4);
    bf16_t* ctxb    = (bf16_t*)alloc((size_t)4096 * 2048 * 2);
    float*  Xg      = (float*) alloc((size_t)2048 * 3072 * 4);
    float*  Lacc    = (float*) alloc((size_t)2048 * 512 * 4);
    float*  cacheK  = (float*) alloc((size_t)4096 * 1024 * 4);
    float*  qg      = (float*) alloc((size_t)64 * 1024 * 4);
    float*  hf      = (float*) alloc((size_t)64 * 1024 * 4);
    bf16_t* hbH     = (bf16_t*)alloc((size_t)64 * 1024 * 2);
    bf16_t* hbL     = (bf16_t*)alloc((size_t)64 * 1024 * 2);
    bf16_t* h1H     = (bf16_t*)alloc((size_t)64 * 1024 * 2);
    bf16_t* h1L     = (bf16_t*)alloc((size_t)64 * 1024 * 2);
    bf16_t* atH     = (bf16_t*)alloc((size_t)64 * 2048 * 2);
    bf16_t* atL     = (bf16_t*)alloc((size_t)64 * 2048 * 2);
    float*  attnseq = (float*) alloc((size_t)2048 * 2048 * 4);
    float*  outseq  = (float*) alloc((size_t)2048 * 1024 * 4);
    float*  scg     = (float*) alloc((size_t)64 * 64 * 4);

    hipMemsetAsync(flags, 0, (NBLK * FLSTR + 8 * FLSTR) * 4, stream);

    embed_kernel<<<(B_*T_*E_/4 + 255)/256, 256, 0, stream>>>(y, emb, x);
    transpose_kernel<<<dim3(1024/32, 2048/32), dim3(32,32), 0, stream>>>(Wk, WkT, 2048, 1024);
    transpose_kernel<<<dim3(1024/32, 1024/32), dim3(32,32), 0, stream>>>(Wq, WqT, 1024, 1024);
    cvt_ctx<<<(4096*2048/8)/256, 256, 0, stream>>>(context, ctxb);

    // prologue GEMMs (split-precision MFMA, f32 in/out)
    sgemm<0><<<dim3(G_/128, 16), 256, 0, stream>>>(x, W_ih1, Xg, G_, E_);
    sgemm<0><<<dim3(E_/128, 16), 256, 0, stream>>>(x, Wi, Lacc, E_, E_);
    sgemm<0><<<dim3(H_/128, 32), 256, 0, stream>>>(context, WkT, cacheK, H_, C_);

    // persistent scan
    hipFuncSetAttribute((const void*)scan_kernel, hipFuncAttributeMaxDynamicSharedMemorySize, SMEM_BYTES);
    scan_kernel<<<NBLK, 1024, SMEM_BYTES, stream>>>(
        W_hh1, W_hh2, WqT, W_ih2, Xg,
        b_ih1, b_hh1, b_ih2, b_hh2, bq, v_attn, cmask, hidden, cacheK, ctxb,
        qg, hf, hbH, hbL, h1H, h1L, atH, atL, attnseq, outseq,
        (float*)d_out + (size_t)B_ * T_ * E_, scg, flags, done);

    // epilogue GEMMs accumulate into Lacc
    sgemm<1><<<dim3(E_/128, 16), 256, 0, stream>>>(outseq, Wh, Lacc, E_, H_);
    sgemm<1><<<dim3(E_/128, 16), 256, 0, stream>>>(attnseq, Wc, Lacc, E_, C_);

    final_kernel<<<(B_*T_*E_)/256, 256, 0, stream>>>(Lacc, bi, bh, bc, (float*)d_out);
}

// Round 7
// 4163.104 us; speedup vs baseline: 8.6815x; 1.1994x over previous
//
#include <hip/hip_runtime.h>
#include <math.h>

#define B_ 64
#define T_ 32
#define S_ 64
#define E_ 512
#define H_ 1024
#define C_ 2048
#define G_ 3072
#define NBLK 256
#define FLSTR 16   // 16 uints = 64B padding per flag slot

typedef __bf16 bf16_t;
typedef bf16_t bf16x8 __attribute__((ext_vector_type(8)));
typedef float f32x4 __attribute__((ext_vector_type(4)));

__device__ __forceinline__ float sigm_(float x) { return 1.f / (1.f + __expf(-x)); }
__device__ __forceinline__ float tanh_(float x) { return 1.f - 2.f / (__expf(2.f * x) + 1.f); }

// split 8 consecutive f32 into hi/lo bf16x8
__device__ __forceinline__ void split8(const float* __restrict__ p, bf16x8& h, bf16x8& l)
{
    float4 a = *(const float4*)p;
    float4 b = *(const float4*)(p + 4);
    float v[8] = {a.x, a.y, a.z, a.w, b.x, b.y, b.z, b.w};
    #pragma unroll
    for (int q = 0; q < 8; ++q) {
        h[q] = (bf16_t)v[q];
        l[q] = (bf16_t)(v[q] - (float)h[q]);
    }
}

// ===================== helpers =====================
__global__ __launch_bounds__(256)
void embed_kernel(const int* __restrict__ y, const float* __restrict__ emb,
                  float* __restrict__ x)
{
    int i = blockIdx.x * 256 + threadIdx.x;      // B*T*E/4
    int row = i / (E_ / 4);
    int e4  = i % (E_ / 4);
    const float4* src = (const float4*)(emb + (size_t)y[row] * E_);
    ((float4*)(x + (size_t)row * E_))[e4] = src[e4];
}

__global__ void transpose_kernel(const float* __restrict__ in, float* __restrict__ out,
                                 int R, int Ccols)   // out[c][r] = in[r][c]
{
    __shared__ float t[32][33];
    int r0 = blockIdx.y * 32, c0 = blockIdx.x * 32;
    t[threadIdx.y][threadIdx.x] = in[(size_t)(r0 + threadIdx.y) * Ccols + c0 + threadIdx.x];
    __syncthreads();
    out[(size_t)(c0 + threadIdx.y) * R + r0 + threadIdx.x] = t[threadIdx.x][threadIdx.y];
}

__global__ __launch_bounds__(256)
void cvt_ctx(const float* __restrict__ in, bf16_t* __restrict__ out)
{
    int i = blockIdx.x * 256 + threadIdx.x;   // over 4096*2048/8
    const float4* s4 = (const float4*)in + 2 * i;
    float4 a = s4[0], b = s4[1];
    bf16x8 o;
    o[0] = (bf16_t)a.x; o[1] = (bf16_t)a.y; o[2] = (bf16_t)a.z; o[3] = (bf16_t)a.w;
    o[4] = (bf16_t)b.x; o[5] = (bf16_t)b.y; o[6] = (bf16_t)b.z; o[7] = (bf16_t)b.w;
    ((bf16x8*)out)[i] = o;
}

// ============ split-precision GEMM: f32 A[M,K] @ f32 Wt[N,K]^T -> f32 =======
#define LSTR 80

template<int ACCUM>
__global__ __launch_bounds__(256)
void sgemm(const float* __restrict__ A, const float* __restrict__ Wt,
           float* __restrict__ out, int N, int K)
{
    __shared__ char AH[128 * LSTR];
    __shared__ char AL[128 * LSTR];
    __shared__ char WH[128 * LSTR];
    __shared__ char WL[128 * LSTR];
    const int tid = threadIdx.x;
    const int lane = tid & 63, wave = tid >> 6;
    const int m0 = blockIdx.y * 128, n0 = blockIdx.x * 128;
    const int wm = (wave & 1) * 64, wn = (wave >> 1) * 64;
    const int l15 = lane & 15, l4 = lane >> 4;

    f32x4 acc[4][4] = {};

    for (int k0 = 0; k0 < K; k0 += 32) {
        #pragma unroll
        for (int p = 0; p < 2; ++p) {
            int e = tid + p * 256;
            int row = e >> 2, ch = e & 3;
            int off = row * LSTR + ch * 16;
            bf16x8 h, l;
            split8(A + (size_t)(m0 + row) * K + k0 + ch * 8, h, l);
            *(bf16x8*)(AH + off) = h; *(bf16x8*)(AL + off) = l;
            split8(Wt + (size_t)(n0 + row) * K + k0 + ch * 8, h, l);
            *(bf16x8*)(WH + off) = h; *(bf16x8*)(WL + off) = l;
        }
        __syncthreads();
        bf16x8 ah[4], al[4], wh[4], wl[4];
        #pragma unroll
        for (int i = 0; i < 4; ++i) {
            int off = (wm + i * 16 + l15) * LSTR + l4 * 16;
            ah[i] = *(const bf16x8*)(AH + off);
            al[i] = *(const bf16x8*)(AL + off);
        }
        #pragma unroll
        for (int j = 0; j < 4; ++j) {
            int off = (wn + j * 16 + l15) * LSTR + l4 * 16;
            wh[j] = *(const bf16x8*)(WH + off);
            wl[j] = *(const bf16x8*)(WL + off);
        }
        #pragma unroll
        for (int i = 0; i < 4; ++i)
            #pragma unroll
            for (int j = 0; j < 4; ++j) {
                acc[i][j] = __builtin_amdgcn_mfma_f32_16x16x32_bf16(ah[i], wh[j], acc[i][j], 0, 0, 0);
                acc[i][j] = __builtin_amdgcn_mfma_f32_16x16x32_bf16(ah[i], wl[j], acc[i][j], 0, 0, 0);
                acc[i][j] = __builtin_amdgcn_mfma_f32_16x16x32_bf16(al[i], wh[j], acc[i][j], 0, 0, 0);
            }
        __syncthreads();
    }

    #pragma unroll
    for (int i = 0; i < 4; ++i)
        #pragma unroll
        for (int j = 0; j < 4; ++j)
            #pragma unroll
            for (int r = 0; r < 4; ++r) {
                int m = m0 + wm + i * 16 + l4 * 4 + r;
                int n = n0 + wn + j * 16 + l15;
                if (ACCUM) out[(size_t)m * N + n] += acc[i][j][r];
                else       out[(size_t)m * N + n]  = acc[i][j][r];
            }
}

// ===================== persistent scan kernel =====================
#define W1H_OFF 0         // W_hh1 hi : 12 rows x 2048B
#define W1L_OFF 24576     // W_hh1 lo : 12 rows
#define W3H_OFF 49152     // W_ih2 hi : 12 rows x 4096B
#define W2H_OFF 98304     // [W_hh2 gates; WqT] hi : 16 rows x 2048B
#define W2L_OFF 131072    // lo : 16 rows -> ends 163840
#define SMEM_BYTES 163840

// Contention-free barrier with RELAXED polls; one release fence before
// signaling, one acquire fence after poll exit, per block per barrier.
__device__ __forceinline__ void gbar(unsigned* flags, unsigned* done,
                                     unsigned epoch, int blk, int tid)
{
    __syncthreads();
    if (blk == 0) {
        if (tid == 0) __builtin_amdgcn_fence(__ATOMIC_RELEASE, "agent");
        if (tid > 0 && tid < NBLK) {
            while (__hip_atomic_load(&flags[tid * FLSTR], __ATOMIC_RELAXED,
                                     __HIP_MEMORY_SCOPE_AGENT) < epoch)
                __builtin_amdgcn_s_sleep(4);
        }
        __syncthreads();
        if (tid < 8)
            __hip_atomic_store(&done[tid * FLSTR], epoch, __ATOMIC_RELAXED,
                               __HIP_MEMORY_SCOPE_AGENT);
        if (tid == 0) __builtin_amdgcn_fence(__ATOMIC_ACQUIRE, "agent");
        __syncthreads();
    } else {
        if (tid == 0) {
            __builtin_amdgcn_fence(__ATOMIC_RELEASE, "agent");
            __hip_atomic_store(&flags[blk * FLSTR], epoch, __ATOMIC_RELAXED,
                               __HIP_MEMORY_SCOPE_AGENT);
            while (__hip_atomic_load(&done[(blk & 7) * FLSTR], __ATOMIC_RELAXED,
                                     __HIP_MEMORY_SCOPE_AGENT) < epoch)
                __builtin_amdgcn_s_sleep(4);
            __builtin_amdgcn_fence(__ATOMIC_ACQUIRE, "agent");
        }
        __syncthreads();
    }
}

__global__ __launch_bounds__(1024, 1)
void scan_kernel(
    const float* __restrict__ Whh1, const float* __restrict__ Whh2,
    const float* __restrict__ WqT,  const float* __restrict__ Wih2,
    const float* __restrict__ Xg,
    const float* __restrict__ b_ih1, const float* __restrict__ b_hh1,
    const float* __restrict__ b_ih2, const float* __restrict__ b_hh2,
    const float* __restrict__ bq,    const float* __restrict__ v_attn,
    const int*   __restrict__ cmask,
    const float* __restrict__ hidden,
    const float* __restrict__ cacheK, const bf16_t* __restrict__ ctxb,
    float* __restrict__ qg, float* __restrict__ hf,
    bf16_t* __restrict__ hbH, bf16_t* __restrict__ hbL,
    bf16_t* __restrict__ h1H, bf16_t* __restrict__ h1L,
    bf16_t* __restrict__ atH, bf16_t* __restrict__ atL,
    float* __restrict__ attnseq, float* __restrict__ outseq,
    float* __restrict__ hfinal,
    float* __restrict__ scg,
    unsigned* __restrict__ flags, unsigned* __restrict__ done)
{
    extern __shared__ char sm[];
    const int tid = threadIdx.x, blk = blockIdx.x;
    const int lane = tid & 63, wave = tid >> 6;   // 16 waves
    const int l15 = lane & 15, l4 = lane >> 4;
    const int blk4 = blk * 4;
    const int ab  = blk & 63;    // attention batch
    const int aq  = blk >> 6;    // attention quarter (0..3)

    // ---- stage weight slices into LDS as hi/lo bf16 (swizzled) ----
    for (int e = tid; e < 12 * 128; e += 1024) {           // W_hh1 (K=1024)
        int r = e >> 7, c = e & 127;
        bf16x8 h, l;
        split8(Whh1 + (size_t)((r >> 2) * 1024 + blk4 + (r & 3)) * 1024 + c * 8, h, l);
        int off = r * 2048 + ((c * 16) ^ ((r & 7) << 4));
        *(bf16x8*)(sm + W1H_OFF + off) = h;
        *(bf16x8*)(sm + W1L_OFF + off) = l;
    }
    for (int e = tid; e < 16 * 128; e += 1024) {           // [W_hh2 gates; WqT] (K=1024)
        int r = e >> 7, c = e & 127;
        const float* src = (r < 12)
            ? Whh2 + (size_t)((r >> 2) * 1024 + blk4 + (r & 3)) * 1024 + c * 8
            : WqT + (size_t)(blk4 + r - 12) * 1024 + c * 8;
        bf16x8 h, l;
        split8(src, h, l);
        int off = r * 2048 + ((c * 16) ^ ((r & 7) << 4));
        *(bf16x8*)(sm + W2H_OFF + off) = h;
        *(bf16x8*)(sm + W2L_OFF + off) = l;
    }
    for (int e = tid; e < 12 * 256; e += 1024) {           // W_ih2 hi only (K=2048)
        int r = e >> 8, c = e & 255;
        bf16x8 h, l;
        split8(Wih2 + (size_t)((r >> 2) * 1024 + blk4 + (r & 3)) * 2048 + c * 8, h, l);
        *(bf16x8*)(sm + W3H_OFF + r * 4096 + ((c * 16) ^ ((r & 7) << 4))) = h;
    }

    if (tid < 256) {   // h init
        int idx = blk * 256 + tid;
        float hv = hidden[idx];
        hf[idx] = hv;
        bf16_t hh = (bf16_t)hv;
        hbH[idx] = hh;
        hbL[idx] = (bf16_t)(hv - (float)hh);
    }

    // attention constants in registers (all blocks participate now)
    float vreg[16], bqreg[16];
    #pragma unroll
    for (int i = 0; i < 16; ++i) {
        vreg[i]  = v_attn[lane + 64 * i];
        bqreg[i] = bq[lane + 64 * i];
    }

    // per-thread GRU biases (MFMA waves, threads with l15 < 4 own hidden index j)
    const int j = blk4 + l15;
    float bi1r = 0, bi1z = 0, bi1n = 0, bh1r = 0, bh1z = 0, bh1n = 0;
    float bi2r = 0, bi2z = 0, bi2n = 0, bh2r = 0, bh2z = 0, bh2n = 0;
    if (wave < 4 && l15 < 4) {
        bi1r = b_ih1[j]; bi1z = b_ih1[1024 + j]; bi1n = b_ih1[2048 + j];
        bh1r = b_hh1[j]; bh1z = b_hh1[1024 + j]; bh1n = b_hh1[2048 + j];
        bi2r = b_ih2[j]; bi2z = b_ih2[1024 + j]; bi2n = b_ih2[2048 + j];
        bh2r = b_hh2[j]; bh2z = b_hh2[1024 + j]; bh2n = b_hh2[2048 + j];
    }

    unsigned epoch = 0;
    gbar(flags, done, ++epoch, blk, tid);

    float h1r_[4] = {0.f, 0.f, 0.f, 0.f};
    f32x4 acc1 = {0.f, 0.f, 0.f, 0.f};

    for (int t = 0; t < T_; ++t) {
        // ===== P0: gh1 = h @ W_hh1^T (split 3-term) + in-register GRU1 =====
        if (wave < 4) {
            f32x4 acc0 = {0.f, 0.f, 0.f, 0.f};
            const bf16_t* ah = hbH + (size_t)(wave * 16 + l15) * 1024;
            const bf16_t* al = hbL + (size_t)(wave * 16 + l15) * 1024;
            #pragma unroll 8
            for (int kk = 0; kk < 32; ++kk) {
                bf16x8 avh = *(const bf16x8*)(ah + kk * 32 + l4 * 8);
                bf16x8 avl = *(const bf16x8*)(al + kk * 32 + l4 * 8);
                int boff = (kk * 64 + l4 * 16) ^ ((l15 & 7) << 4);
                bf16x8 bvh = *(const bf16x8*)(sm + W1H_OFF + l15 * 2048 + boff);
                bf16x8 bvl = *(const bf16x8*)(sm + W1L_OFF + l15 * 2048 + boff);
                acc0 = __builtin_amdgcn_mfma_f32_16x16x32_bf16(avh, bvh, acc0, 0, 0, 0);
                acc0 = __builtin_amdgcn_mfma_f32_16x16x32_bf16(avl, bvh, acc0, 0, 0, 0);
                acc0 = __builtin_amdgcn_mfma_f32_16x16x32_bf16(avh, bvl, acc0, 0, 0, 0);
            }
            #pragma unroll
            for (int r2 = 0; r2 < 4; ++r2) {
                float gr = acc0[r2];
                float gz = __shfl(acc0[r2], (lane & 48) | (l15 + 4), 64);
                float gn = __shfl(acc0[r2], (lane & 48) | (l15 + 8), 64);
                if (l15 < 4) {
                    int b = wave * 16 + l4 * 4 + r2;
                    const float* xg = Xg + ((size_t)b * T_ + t) * 3072;
                    float rr = sigm_(xg[j]          + bi1r + gr + bh1r);
                    float zz = sigm_(xg[1024 + j]   + bi1z + gz + bh1z);
                    float nn = tanh_(xg[2048 + j]   + bi1n + rr * (gn + bh1n));
                    float h1v = (1.f - zz) * nn + zz * hf[b * 1024 + j];
                    h1r_[r2] = h1v;
                    bf16_t hh = (bf16_t)h1v;
                    h1H[b * 1024 + j] = hh;
                    h1L[b * 1024 + j] = (bf16_t)(h1v - (float)hh);
                }
            }
        }
        gbar(flags, done, ++epoch, blk, tid);

        // ===== P1: [gh2 | q] = h1 @ [W_hh2 ; WqT]^T (split 3-term) =====
        if (wave < 4) {
            acc1 = (f32x4){0.f, 0.f, 0.f, 0.f};
            const bf16_t* ah = h1H + (size_t)(wave * 16 + l15) * 1024;
            const bf16_t* al = h1L + (size_t)(wave * 16 + l15) * 1024;
            #pragma unroll 8
            for (int kk = 0; kk < 32; ++kk) {
                bf16x8 avh = *(const bf16x8*)(ah + kk * 32 + l4 * 8);
                bf16x8 avl = *(const bf16x8*)(al + kk * 32 + l4 * 8);
                int boff = (kk * 64 + l4 * 16) ^ ((l15 & 7) << 4);
                bf16x8 bvh = *(const bf16x8*)(sm + W2H_OFF + l15 * 2048 + boff);
                bf16x8 bvl = *(const bf16x8*)(sm + W2L_OFF + l15 * 2048 + boff);
                acc1 = __builtin_amdgcn_mfma_f32_16x16x32_bf16(avh, bvh, acc1, 0, 0, 0);
                acc1 = __builtin_amdgcn_mfma_f32_16x16x32_bf16(avl, bvh, acc1, 0, 0, 0);
                acc1 = __builtin_amdgcn_mfma_f32_16x16x32_bf16(avh, bvl, acc1, 0, 0, 0);
            }
            if (l15 >= 12) {
                int jq = blk4 + l15 - 12;
                #pragma unroll
                for (int r2 = 0; r2 < 4; ++r2)
                    qg[(wave * 16 + l4 * 4 + r2) * 1024 + jq] = acc1[r2];
            }
        }
        gbar(flags, done, ++epoch, blk, tid);

        // ===== P2a: scores (256 blocks: batch ab, quarter aq; one s per wave) =====
        {
            int s = aq * 16 + wave;
            const float* ck = cacheK + ((size_t)ab * 64 + s) * 1024;
            float sum = 0.f;
            #pragma unroll
            for (int i = 0; i < 16; ++i)
                sum += tanh_(qg[ab * 1024 + lane + 64 * i] + bqreg[i] + ck[lane + 64 * i]) * vreg[i];
            #pragma unroll
            for (int off = 32; off; off >>= 1) sum += __shfl_down(sum, off, 64);
            if (lane == 0) scg[ab * 64 + s] = sum;
        }
        gbar(flags, done, ++epoch, blk, tid);

        // ===== P2b: softmax + PV (block covers 512 cols = quarter aq) =====
        if (tid < 256) {
            // per-wave redundant softmax (lane holds s = lane)
            float v = (cmask[ab * 64 + lane] != 0) ? -3.4e38f : scg[ab * 64 + lane];
            float mx = v;
            #pragma unroll
            for (int off = 32; off; off >>= 1) mx = fmaxf(mx, __shfl_xor(mx, off, 64));
            float e = __expf(v - mx);
            float sden = e;
            #pragma unroll
            for (int off = 32; off; off >>= 1) sden += __shfl_xor(sden, off, 64);
            float prv = e / sden;

            int c = aq * 512 + tid * 2;     // column pair
            const bf16_t* cb = ctxb + (size_t)ab * 64 * 2048 + c;
            float sum0 = 0.f, sum1 = 0.f;
            #pragma unroll 8
            for (int s = 0; s < 64; ++s) {
                float p = __shfl(prv, s, 64);
                bf16_t v0 = cb[(size_t)s * 2048];
                bf16_t v1 = cb[(size_t)s * 2048 + 1];
                sum0 += p * (float)v0;
                sum1 += p * (float)v1;
            }
            float* as = attnseq + ((size_t)ab * T_ + t) * 2048 + c;
            as[0] = sum0; as[1] = sum1;
            bf16_t h0 = (bf16_t)sum0, h1v = (bf16_t)sum1;
            atH[ab * 2048 + c]     = h0;
            atL[ab * 2048 + c]     = (bf16_t)(sum0 - (float)h0);
            atH[ab * 2048 + c + 1] = h1v;
            atL[ab * 2048 + c + 1] = (bf16_t)(sum1 - (float)h1v);
        }
        gbar(flags, done, ++epoch, blk, tid);

        // ===== P3: gi2 = attn @ W_ih2^T (A split, W hi) + GRU2 =====
        if (wave < 4) {
            f32x4 acc3 = {0.f, 0.f, 0.f, 0.f};
            const bf16_t* ah = atH + (size_t)(wave * 16 + l15) * 2048;
            const bf16_t* al = atL + (size_t)(wave * 16 + l15) * 2048;
            #pragma unroll 8
            for (int kk = 0; kk < 64; ++kk) {
                bf16x8 avh = *(const bf16x8*)(ah + kk * 32 + l4 * 8);
                bf16x8 avl = *(const bf16x8*)(al + kk * 32 + l4 * 8);
                bf16x8 bvh = *(const bf16x8*)(sm + W3H_OFF + l15 * 4096 +
                                              ((kk * 64 + l4 * 16) ^ ((l15 & 7) << 4)));
                acc3 = __builtin_amdgcn_mfma_f32_16x16x32_bf16(avh, bvh, acc3, 0, 0, 0);
                acc3 = __builtin_amdgcn_mfma_f32_16x16x32_bf16(avl, bvh, acc3, 0, 0, 0);
            }
            #pragma unroll
            for (int r2 = 0; r2 < 4; ++r2) {
                float ir  = acc3[r2];
                float iz  = __shfl(acc3[r2], (lane & 48) | (l15 + 4), 64);
                float in2 = __shfl(acc3[r2], (lane & 48) | (l15 + 8), 64);
                float hr  = acc1[r2];
                float hz  = __shfl(acc1[r2], (lane & 48) | (l15 + 4), 64);
                float hn  = __shfl(acc1[r2], (lane & 48) | (l15 + 8), 64);
                if (l15 < 4) {
                    int b = wave * 16 + l4 * 4 + r2;
                    float rr = sigm_(ir + bi2r + hr + bh2r);
                    float zz = sigm_(iz + bi2z + hz + bh2z);
                    float nn = tanh_(in2 + bi2n + rr * (hn + bh2n));
                    float h2 = (1.f - zz) * nn + zz * h1r_[r2];
                    hf[b * 1024 + j] = h2;
                    bf16_t hh = (bf16_t)h2;
                    hbH[b * 1024 + j] = hh;
                    hbL[b * 1024 + j] = (bf16_t)(h2 - (float)hh);
                    outseq[((size_t)b * T_ + t) * 1024 + j] = h2;
                    if (t == T_ - 1) hfinal[b * 1024 + j] = h2;
                }
            }
        }
        gbar(flags, done, ++epoch, blk, tid);
    }
}

// ===================== final logits =====================
__global__ __launch_bounds__(256)
void final_kernel(const float* __restrict__ Lacc,
                  const float* __restrict__ bi, const float* __restrict__ bh,
                  const float* __restrict__ bc, float* __restrict__ out)
{
    int i = blockIdx.x * 256 + threadIdx.x;
    int e = i & 511;
    out[i] = tanh_(Lacc[i] + bi[e] + bh[e] + bc[e]);
}

// ===================== host =====================
extern "C" void kernel_launch(void* const* d_in, const int* in_sizes, int n_in,
                              void* d_out, int out_size, void* d_ws, size_t ws_size,
                              hipStream_t stream)
{
    const int*   y       = (const int*)  d_in[0];
    const float* context = (const float*)d_in[1];
    const int*   cmask   = (const int*)  d_in[2];
    const float* hidden  = (const float*)d_in[3];
    const float* emb     = (const float*)d_in[4];
    const float* W_ih1   = (const float*)d_in[5];
    const float* W_hh1   = (const float*)d_in[6];
    const float* b_ih1   = (const float*)d_in[7];
    const float* b_hh1   = (const float*)d_in[8];
    const float* Wq      = (const float*)d_in[9];
    const float* bq      = (const float*)d_in[10];
    const float* Wk      = (const float*)d_in[11];
    const float* v_attn  = (const float*)d_in[12];
    const float* W_ih2   = (const float*)d_in[13];
    const float* W_hh2   = (const float*)d_in[14];
    const float* b_ih2   = (const float*)d_in[15];
    const float* b_hh2   = (const float*)d_in[16];
    const float* Wi      = (const float*)d_in[17];
    const float* bi      = (const float*)d_in[18];
    const float* Wh      = (const float*)d_in[19];
    const float* bh      = (const float*)d_in[20];
    const float* Wc      = (const float*)d_in[21];
    const float* bc      = (const float*)d_in[22];

    char* ws = (char*)d_ws;
    size_t o = 0;
    auto alloc = [&](size_t bytes) { char* p = ws + o; o += (bytes + 255) & ~(size_t)255; return p; };
    unsigned* flags = (unsigned*)alloc(NBLK * FLSTR * 4);   // 16 KB
    unsigned* done  = (unsigned*)alloc(8 * FLSTR * 4);      // 512 B
    float*  x       = (float*) alloc((size_t)2048 * 512 * 4);
    float*  WkT     = (float*) alloc((size_t)1024 * 2048 * 4);
    float*  WqT     = (float*) alloc((size_t)1024 * 1024 * 4);
    bf16_t* ctxb    = (bf16_t*)alloc((size_t)4096 * 2048 * 2);
    float*  Xg      = (float*) alloc((size_t)2048 * 3072 * 4);
    float*  Lacc    = (float*) alloc((size_t)2048 * 512 * 4);
    float*  cacheK  = (float*) alloc((size_t)4096 * 1024 * 4);
    float*  qg      = (float*) alloc((size_t)64 * 1024 * 4);
    float*  hf      = (float*) alloc((size_t)64 * 1024 * 4);
    bf16_t* hbH     = (bf16_t*)alloc((size_t)64 * 1024 * 2);
    bf16_t* hbL     = (bf16_t*)alloc((size_t)64 * 1024 * 2);
    bf16_t* h1H     = (bf16_t*)alloc((size_t)64 * 1024 * 2);
    bf16_t* h1L     = (bf16_t*)alloc((size_t)64 * 1024 * 2);
    bf16_t* atH     = (bf16_t*)alloc((size_t)64 * 2048 * 2);
    bf16_t* atL     = (bf16_t*)alloc((size_t)64 * 2048 * 2);
    float*  attnseq = (float*) alloc((size_t)2048 * 2048 * 4);
    float*  outseq  = (float*) alloc((size_t)2048 * 1024 * 4);
    float*  scg     = (float*) alloc((size_t)64 * 64 * 4);

    hipMemsetAsync(flags, 0, (NBLK * FLSTR + 8 * FLSTR) * 4, stream);

    embed_kernel<<<(B_*T_*E_/4 + 255)/256, 256, 0, stream>>>(y, emb, x);
    transpose_kernel<<<dim3(1024/32, 2048/32), dim3(32,32), 0, stream>>>(Wk, WkT, 2048, 1024);
    transpose_kernel<<<dim3(1024/32, 1024/32), dim3(32,32), 0, stream>>>(Wq, WqT, 1024, 1024);
    cvt_ctx<<<(4096*2048/8)/256, 256, 0, stream>>>(context, ctxb);

    // prologue GEMMs (split-precision MFMA, f32 in/out)
    sgemm<0><<<dim3(G_/128, 16), 256, 0, stream>>>(x, W_ih1, Xg, G_, E_);
    sgemm<0><<<dim3(E_/128, 16), 256, 0, stream>>>(x, Wi, Lacc, E_, E_);
    sgemm<0><<<dim3(H_/128, 32), 256, 0, stream>>>(context, WkT, cacheK, H_, C_);

    // persistent scan
    hipFuncSetAttribute((const void*)scan_kernel, hipFuncAttributeMaxDynamicSharedMemorySize, SMEM_BYTES);
    scan_kernel<<<NBLK, 1024, SMEM_BYTES, stream>>>(
        W_hh1, W_hh2, WqT, W_ih2, Xg,
        b_ih1, b_hh1, b_ih2, b_hh2, bq, v_attn, cmask, hidden, cacheK, ctxb,
        qg, hf, hbH, hbL, h1H, h1L, atH, atL, attnseq, outseq,
        (float*)d_out + (size_t)B_ * T_ * E_, scg, flags, done);

    // epilogue GEMMs accumulate into Lacc
    sgemm<1><<<dim3(E_/128, 16), 256, 0, stream>>>(outseq, Wh, Lacc, E_, H_);
    sgemm<1><<<dim3(E_/128, 16), 256, 0, stream>>>(attnseq, Wc, Lacc, E_, C_);

    final_kernel<<<(B_*T_*E_)/256, 256, 0, stream>>>(Lacc, bi, bh, bc, (float*)d_out);
}

// Round 8
// 3725.958 us; speedup vs baseline: 9.7000x; 1.1173x over previous
//
#include <hip/hip_runtime.h>
#include <math.h>

#define B_ 64
#define T_ 32
#define S_ 64
#define E_ 512
#define H_ 1024
#define C_ 2048
#define G_ 3072
#define NBLK 256
#define FLSTR 16   // 16 uints = 64B padding per flag slot

typedef __bf16 bf16_t;
typedef bf16_t bf16x8 __attribute__((ext_vector_type(8)));
typedef bf16_t bf16x4 __attribute__((ext_vector_type(4)));
typedef float f32x4 __attribute__((ext_vector_type(4)));
typedef unsigned long long u64;

__device__ __forceinline__ float sigm_(float x) { return 1.f / (1.f + __expf(-x)); }
__device__ __forceinline__ float tanh_(float x) { return 1.f - 2.f / (__expf(2.f * x) + 1.f); }

// ---- relaxed agent-scope (L2-bypassing) access helpers ----
__device__ __forceinline__ bf16x8 aload16(const bf16_t* p)
{
    u64 a = __hip_atomic_load((const u64*)p,       __ATOMIC_RELAXED, __HIP_MEMORY_SCOPE_AGENT);
    u64 b = __hip_atomic_load((const u64*)(p + 4), __ATOMIC_RELAXED, __HIP_MEMORY_SCOPE_AGENT);
    union { u64 u; bf16x4 v; } ua, ub;
    ua.u = a; ub.u = b;
    return __builtin_shufflevector(ua.v, ub.v, 0, 1, 2, 3, 4, 5, 6, 7);
}
__device__ __forceinline__ unsigned short bits_(bf16_t x)
{
    union { bf16_t b; unsigned short u; } c; c.b = x; return c.u;
}
__device__ __forceinline__ void astore_pair(bf16_t* p, bf16_t lo, bf16_t hi)
{
    unsigned u = (unsigned)bits_(lo) | ((unsigned)bits_(hi) << 16);
    __hip_atomic_store((unsigned*)p, u, __ATOMIC_RELAXED, __HIP_MEMORY_SCOPE_AGENT);
}
__device__ __forceinline__ void astore_f32(float* p, float v)
{
    union { float f; unsigned u; } c; c.f = v;
    __hip_atomic_store((unsigned*)p, c.u, __ATOMIC_RELAXED, __HIP_MEMORY_SCOPE_AGENT);
}
__device__ __forceinline__ float aload_f32(const float* p)
{
    unsigned u = __hip_atomic_load((const unsigned*)p, __ATOMIC_RELAXED, __HIP_MEMORY_SCOPE_AGENT);
    union { unsigned u; float f; } c; c.u = u; return c.f;
}

// split 8 consecutive f32 into hi/lo bf16x8
__device__ __forceinline__ void split8(const float* __restrict__ p, bf16x8& h, bf16x8& l)
{
    float4 a = *(const float4*)p;
    float4 b = *(const float4*)(p + 4);
    float v[8] = {a.x, a.y, a.z, a.w, b.x, b.y, b.z, b.w};
    #pragma unroll
    for (int q = 0; q < 8; ++q) {
        h[q] = (bf16_t)v[q];
        l[q] = (bf16_t)(v[q] - (float)h[q]);
    }
}

// ===================== helpers =====================
__global__ __launch_bounds__(256)
void embed_kernel(const int* __restrict__ y, const float* __restrict__ emb,
                  float* __restrict__ x)
{
    int i = blockIdx.x * 256 + threadIdx.x;      // B*T*E/4
    int row = i / (E_ / 4);
    int e4  = i % (E_ / 4);
    const float4* src = (const float4*)(emb + (size_t)y[row] * E_);
    ((float4*)(x + (size_t)row * E_))[e4] = src[e4];
}

__global__ void transpose_kernel(const float* __restrict__ in, float* __restrict__ out,
                                 int R, int Ccols)
{
    __shared__ float t[32][33];
    int r0 = blockIdx.y * 32, c0 = blockIdx.x * 32;
    t[threadIdx.y][threadIdx.x] = in[(size_t)(r0 + threadIdx.y) * Ccols + c0 + threadIdx.x];
    __syncthreads();
    out[(size_t)(c0 + threadIdx.y) * R + r0 + threadIdx.x] = t[threadIdx.x][threadIdx.y];
}

__global__ __launch_bounds__(256)
void cvt_ctx(const float* __restrict__ in, bf16_t* __restrict__ out)
{
    int i = blockIdx.x * 256 + threadIdx.x;
    const float4* s4 = (const float4*)in + 2 * i;
    float4 a = s4[0], b = s4[1];
    bf16x8 o;
    o[0] = (bf16_t)a.x; o[1] = (bf16_t)a.y; o[2] = (bf16_t)a.z; o[3] = (bf16_t)a.w;
    o[4] = (bf16_t)b.x; o[5] = (bf16_t)b.y; o[6] = (bf16_t)b.z; o[7] = (bf16_t)b.w;
    ((bf16x8*)out)[i] = o;
}

// ============ split-precision GEMM: f32 A[M,K] @ f32 Wt[N,K]^T -> f32 =======
#define LSTR 80

template<int ACCUM>
__global__ __launch_bounds__(256)
void sgemm(const float* __restrict__ A, const float* __restrict__ Wt,
           float* __restrict__ out, int N, int K)
{
    __shared__ char AH[128 * LSTR];
    __shared__ char AL[128 * LSTR];
    __shared__ char WH[128 * LSTR];
    __shared__ char WL[128 * LSTR];
    const int tid = threadIdx.x;
    const int lane = tid & 63, wave = tid >> 6;
    const int m0 = blockIdx.y * 128, n0 = blockIdx.x * 128;
    const int wm = (wave & 1) * 64, wn = (wave >> 1) * 64;
    const int l15 = lane & 15, l4 = lane >> 4;

    f32x4 acc[4][4] = {};

    for (int k0 = 0; k0 < K; k0 += 32) {
        #pragma unroll
        for (int p = 0; p < 2; ++p) {
            int e = tid + p * 256;
            int row = e >> 2, ch = e & 3;
            int off = row * LSTR + ch * 16;
            bf16x8 h, l;
            split8(A + (size_t)(m0 + row) * K + k0 + ch * 8, h, l);
            *(bf16x8*)(AH + off) = h; *(bf16x8*)(AL + off) = l;
            split8(Wt + (size_t)(n0 + row) * K + k0 + ch * 8, h, l);
            *(bf16x8*)(WH + off) = h; *(bf16x8*)(WL + off) = l;
        }
        __syncthreads();
        bf16x8 ah[4], al[4], wh[4], wl[4];
        #pragma unroll
        for (int i = 0; i < 4; ++i) {
            int off = (wm + i * 16 + l15) * LSTR + l4 * 16;
            ah[i] = *(const bf16x8*)(AH + off);
            al[i] = *(const bf16x8*)(AL + off);
        }
        #pragma unroll
        for (int j = 0; j < 4; ++j) {
            int off = (wn + j * 16 + l15) * LSTR + l4 * 16;
            wh[j] = *(const bf16x8*)(WH + off);
            wl[j] = *(const bf16x8*)(WL + off);
        }
        #pragma unroll
        for (int i = 0; i < 4; ++i)
            #pragma unroll
            for (int j = 0; j < 4; ++j) {
                acc[i][j] = __builtin_amdgcn_mfma_f32_16x16x32_bf16(ah[i], wh[j], acc[i][j], 0, 0, 0);
                acc[i][j] = __builtin_amdgcn_mfma_f32_16x16x32_bf16(ah[i], wl[j], acc[i][j], 0, 0, 0);
                acc[i][j] = __builtin_amdgcn_mfma_f32_16x16x32_bf16(al[i], wh[j], acc[i][j], 0, 0, 0);
            }
        __syncthreads();
    }

    #pragma unroll
    for (int i = 0; i < 4; ++i)
        #pragma unroll
        for (int j = 0; j < 4; ++j)
            #pragma unroll
            for (int r = 0; r < 4; ++r) {
                int m = m0 + wm + i * 16 + l4 * 4 + r;
                int n = n0 + wn + j * 16 + l15;
                if (ACCUM) out[(size_t)m * N + n] += acc[i][j][r];
                else       out[(size_t)m * N + n]  = acc[i][j][r];
            }
}

// ===================== persistent scan kernel =====================
#define W1H_OFF 0         // W_hh1 hi : 12 rows x 2048B
#define W1L_OFF 24576     // W_hh1 lo : 12 rows
#define W3H_OFF 49152     // W_ih2 hi : 12 rows x 4096B
#define W2H_OFF 98304     // [W_hh2 gates; WqT] hi : 16 rows x 2048B
#define W2L_OFF 131072    // lo : 16 rows -> ends 163840
#define SMEM_BYTES 163840

// Fence-free barrier: __syncthreads drains each wave's vmem stores (the
// bypassing relaxed-agent stores complete at the coherence point); flags are
// relaxed agent atomics. NO acquire/release fences -> L2 is never invalidated.
__device__ __forceinline__ void gbar(unsigned* flags, unsigned* done,
                                     unsigned epoch, int blk, int tid)
{
    asm volatile("s_waitcnt vmcnt(0)" ::: "memory");
    __syncthreads();
    if (blk == 0) {
        if (tid > 0 && tid < NBLK) {
            while (__hip_atomic_load(&flags[tid * FLSTR], __ATOMIC_RELAXED,
                                     __HIP_MEMORY_SCOPE_AGENT) < epoch)
                __builtin_amdgcn_s_sleep(4);
        }
        __syncthreads();
        if (tid < 8)
            __hip_atomic_store(&done[tid * FLSTR], epoch, __ATOMIC_RELAXED,
                               __HIP_MEMORY_SCOPE_AGENT);
        __syncthreads();
    } else {
        if (tid == 0) {
            __hip_atomic_store(&flags[blk * FLSTR], epoch, __ATOMIC_RELAXED,
                               __HIP_MEMORY_SCOPE_AGENT);
            while (__hip_atomic_load(&done[(blk & 7) * FLSTR], __ATOMIC_RELAXED,
                                     __HIP_MEMORY_SCOPE_AGENT) < epoch)
                __builtin_amdgcn_s_sleep(4);
        }
        __syncthreads();
    }
}

__global__ __launch_bounds__(1024, 1)
void scan_kernel(
    const float* __restrict__ Whh1, const float* __restrict__ Whh2,
    const float* __restrict__ WqT,  const float* __restrict__ Wih2,
    const float* __restrict__ Xg,
    const float* __restrict__ b_ih1, const float* __restrict__ b_hh1,
    const float* __restrict__ b_ih2, const float* __restrict__ b_hh2,
    const float* __restrict__ bq,    const float* __restrict__ v_attn,
    const int*   __restrict__ cmask,
    const float* __restrict__ hidden,
    const float* __restrict__ cacheK, const bf16_t* __restrict__ ctxb,
    float* __restrict__ qg, float* __restrict__ hf,
    bf16_t* __restrict__ hbH, bf16_t* __restrict__ hbL,
    bf16_t* __restrict__ h1H, bf16_t* __restrict__ h1L,
    bf16_t* __restrict__ atH, bf16_t* __restrict__ atL,
    float* __restrict__ attnseq, float* __restrict__ outseq,
    float* __restrict__ hfinal,
    float* __restrict__ scg,
    unsigned* __restrict__ flags, unsigned* __restrict__ done)
{
    extern __shared__ char sm[];
    const int tid = threadIdx.x, blk = blockIdx.x;
    const int lane = tid & 63, wave = tid >> 6;   // 16 waves
    const int l15 = lane & 15, l4 = lane >> 4;
    const int blk4 = blk * 4;
    const int ab  = blk & 63;    // attention batch
    const int aq  = blk >> 6;    // attention quarter (0..3)

    // ---- stage weight slices into LDS as hi/lo bf16 (swizzled) ----
    for (int e = tid; e < 12 * 128; e += 1024) {           // W_hh1 (K=1024)
        int r = e >> 7, c = e & 127;
        bf16x8 h, l;
        split8(Whh1 + (size_t)((r >> 2) * 1024 + blk4 + (r & 3)) * 1024 + c * 8, h, l);
        int off = r * 2048 + ((c * 16) ^ ((r & 7) << 4));
        *(bf16x8*)(sm + W1H_OFF + off) = h;
        *(bf16x8*)(sm + W1L_OFF + off) = l;
    }
    for (int e = tid; e < 16 * 128; e += 1024) {           // [W_hh2 gates; WqT] (K=1024)
        int r = e >> 7, c = e & 127;
        const float* src = (r < 12)
            ? Whh2 + (size_t)((r >> 2) * 1024 + blk4 + (r & 3)) * 1024 + c * 8
            : WqT + (size_t)(blk4 + r - 12) * 1024 + c * 8;
        bf16x8 h, l;
        split8(src, h, l);
        int off = r * 2048 + ((c * 16) ^ ((r & 7) << 4));
        *(bf16x8*)(sm + W2H_OFF + off) = h;
        *(bf16x8*)(sm + W2L_OFF + off) = l;
    }
    for (int e = tid; e < 12 * 256; e += 1024) {           // W_ih2 hi only (K=2048)
        int r = e >> 8, c = e & 255;
        bf16x8 h, l;
        split8(Wih2 + (size_t)((r >> 2) * 1024 + blk4 + (r & 3)) * 2048 + c * 8, h, l);
        *(bf16x8*)(sm + W3H_OFF + r * 4096 + ((c * 16) ^ ((r & 7) << 4))) = h;
    }

    // h init: hb via bypass stores (cross-block), hf by owning thread (local)
    if (tid < 128) {
        int idx = blk * 256 + tid * 2;
        float v0 = hidden[idx], v1 = hidden[idx + 1];
        bf16_t h0 = (bf16_t)v0, h1x = (bf16_t)v1;
        astore_pair(hbH + idx, h0, h1x);
        astore_pair(hbL + idx, (bf16_t)(v0 - (float)h0), (bf16_t)(v1 - (float)h1x));
    }
    const int j = blk4 + l15;
    if (wave < 4 && l15 < 4) {
        #pragma unroll
        for (int r2 = 0; r2 < 4; ++r2) {
            int b = wave * 16 + l4 * 4 + r2;
            hf[b * 1024 + j] = hidden[b * 1024 + j];
        }
    }

    // attention constants in registers
    float vreg[16], bqreg[16];
    #pragma unroll
    for (int i = 0; i < 16; ++i) {
        vreg[i]  = v_attn[lane + 64 * i];
        bqreg[i] = bq[lane + 64 * i];
    }

    // per-thread GRU biases
    float bi1r = 0, bi1z = 0, bi1n = 0, bh1r = 0, bh1z = 0, bh1n = 0;
    float bi2r = 0, bi2z = 0, bi2n = 0, bh2r = 0, bh2z = 0, bh2n = 0;
    if (wave < 4 && l15 < 4) {
        bi1r = b_ih1[j]; bi1z = b_ih1[1024 + j]; bi1n = b_ih1[2048 + j];
        bh1r = b_hh1[j]; bh1z = b_hh1[1024 + j]; bh1n = b_hh1[2048 + j];
        bi2r = b_ih2[j]; bi2z = b_ih2[1024 + j]; bi2n = b_ih2[2048 + j];
        bh2r = b_hh2[j]; bh2z = b_hh2[1024 + j]; bh2n = b_hh2[2048 + j];
    }

    unsigned epoch = 0;
    gbar(flags, done, ++epoch, blk, tid);

    float h1r_[4] = {0.f, 0.f, 0.f, 0.f};
    f32x4 acc1 = {0.f, 0.f, 0.f, 0.f};

    for (int t = 0; t < T_; ++t) {
        // ===== P0: gh1 = h @ W_hh1^T (split 3-term) + in-register GRU1 =====
        if (wave < 4) {
            f32x4 acc0 = {0.f, 0.f, 0.f, 0.f};
            const bf16_t* ah = hbH + (size_t)(wave * 16 + l15) * 1024;
            const bf16_t* al = hbL + (size_t)(wave * 16 + l15) * 1024;
            #pragma unroll 8
            for (int kk = 0; kk < 32; ++kk) {
                bf16x8 avh = aload16(ah + kk * 32 + l4 * 8);
                bf16x8 avl = aload16(al + kk * 32 + l4 * 8);
                int boff = (kk * 64 + l4 * 16) ^ ((l15 & 7) << 4);
                bf16x8 bvh = *(const bf16x8*)(sm + W1H_OFF + l15 * 2048 + boff);
                bf16x8 bvl = *(const bf16x8*)(sm + W1L_OFF + l15 * 2048 + boff);
                acc0 = __builtin_amdgcn_mfma_f32_16x16x32_bf16(avh, bvh, acc0, 0, 0, 0);
                acc0 = __builtin_amdgcn_mfma_f32_16x16x32_bf16(avl, bvh, acc0, 0, 0, 0);
                acc0 = __builtin_amdgcn_mfma_f32_16x16x32_bf16(avh, bvl, acc0, 0, 0, 0);
            }
            #pragma unroll
            for (int r2 = 0; r2 < 4; ++r2) {
                float gr = acc0[r2];
                float gz = __shfl(acc0[r2], (lane & 48) | (l15 + 4), 64);
                float gn = __shfl(acc0[r2], (lane & 48) | (l15 + 8), 64);
                float h1v = 0.f;
                int b = wave * 16 + l4 * 4 + r2;
                if (l15 < 4) {
                    const float* xg = Xg + ((size_t)b * T_ + t) * 3072;
                    float rr = sigm_(xg[j]          + bi1r + gr + bh1r);
                    float zz = sigm_(xg[1024 + j]   + bi1z + gz + bh1z);
                    float nn = tanh_(xg[2048 + j]   + bi1n + rr * (gn + bh1n));
                    h1v = (1.f - zz) * nn + zz * hf[b * 1024 + j];
                    h1r_[r2] = h1v;
                }
                float h1o = __shfl(h1v, lane + 1, 64);
                if (l15 < 4 && (l15 & 1) == 0) {
                    bf16_t hS = (bf16_t)h1v, hO = (bf16_t)h1o;
                    astore_pair(h1H + b * 1024 + j, hS, hO);
                    astore_pair(h1L + b * 1024 + j,
                                (bf16_t)(h1v - (float)hS), (bf16_t)(h1o - (float)hO));
                }
            }
        }
        gbar(flags, done, ++epoch, blk, tid);

        // ===== P1: [gh2 | q] = h1 @ [W_hh2 ; WqT]^T (split 3-term) =====
        if (wave < 4) {
            acc1 = (f32x4){0.f, 0.f, 0.f, 0.f};
            const bf16_t* ah = h1H + (size_t)(wave * 16 + l15) * 1024;
            const bf16_t* al = h1L + (size_t)(wave * 16 + l15) * 1024;
            #pragma unroll 8
            for (int kk = 0; kk < 32; ++kk) {
                bf16x8 avh = aload16(ah + kk * 32 + l4 * 8);
                bf16x8 avl = aload16(al + kk * 32 + l4 * 8);
                int boff = (kk * 64 + l4 * 16) ^ ((l15 & 7) << 4);
                bf16x8 bvh = *(const bf16x8*)(sm + W2H_OFF + l15 * 2048 + boff);
                bf16x8 bvl = *(const bf16x8*)(sm + W2L_OFF + l15 * 2048 + boff);
                acc1 = __builtin_amdgcn_mfma_f32_16x16x32_bf16(avh, bvh, acc1, 0, 0, 0);
                acc1 = __builtin_amdgcn_mfma_f32_16x16x32_bf16(avl, bvh, acc1, 0, 0, 0);
                acc1 = __builtin_amdgcn_mfma_f32_16x16x32_bf16(avh, bvl, acc1, 0, 0, 0);
            }
            if (l15 >= 12) {
                int jq = blk4 + l15 - 12;
                #pragma unroll
                for (int r2 = 0; r2 < 4; ++r2)
                    astore_f32(&qg[(wave * 16 + l4 * 4 + r2) * 1024 + jq], acc1[r2]);
            }
        }
        gbar(flags, done, ++epoch, blk, tid);

        // ===== P2a: scores (batch ab, quarter aq; one s per wave) =====
        {
            int s = aq * 16 + wave;
            const float* ck = cacheK + ((size_t)ab * 64 + s) * 1024;
            float sum = 0.f;
            #pragma unroll
            for (int i = 0; i < 16; ++i)
                sum += tanh_(aload_f32(&qg[ab * 1024 + lane + 64 * i]) + bqreg[i]
                             + ck[lane + 64 * i]) * vreg[i];
            #pragma unroll
            for (int off = 32; off; off >>= 1) sum += __shfl_down(sum, off, 64);
            if (lane == 0) astore_f32(&scg[ab * 64 + s], sum);
        }
        gbar(flags, done, ++epoch, blk, tid);

        // ===== P2b: softmax + PV (block covers 512 cols = quarter aq) =====
        if (tid < 256) {
            float v = (cmask[ab * 64 + lane] != 0) ? -3.4e38f : aload_f32(&scg[ab * 64 + lane]);
            float mx = v;
            #pragma unroll
            for (int off = 32; off; off >>= 1) mx = fmaxf(mx, __shfl_xor(mx, off, 64));
            float e = __expf(v - mx);
            float sden = e;
            #pragma unroll
            for (int off = 32; off; off >>= 1) sden += __shfl_xor(sden, off, 64);
            float prv = e / sden;

            int c = aq * 512 + tid * 2;
            const bf16_t* cb = ctxb + (size_t)ab * 64 * 2048 + c;
            float sum0 = 0.f, sum1 = 0.f;
            #pragma unroll 8
            for (int s = 0; s < 64; ++s) {
                float p = __shfl(prv, s, 64);
                bf16_t v0 = cb[(size_t)s * 2048];
                bf16_t v1 = cb[(size_t)s * 2048 + 1];
                sum0 += p * (float)v0;
                sum1 += p * (float)v1;
            }
            float* as = attnseq + ((size_t)ab * T_ + t) * 2048 + c;
            as[0] = sum0; as[1] = sum1;
            bf16_t h0 = (bf16_t)sum0, h1v = (bf16_t)sum1;
            astore_pair(atH + ab * 2048 + c, h0, h1v);
            astore_pair(atL + ab * 2048 + c,
                        (bf16_t)(sum0 - (float)h0), (bf16_t)(sum1 - (float)h1v));
        }
        gbar(flags, done, ++epoch, blk, tid);

        // ===== P3: gi2 = attn @ W_ih2^T (A split, W hi) + GRU2 =====
        if (wave < 4) {
            f32x4 acc3 = {0.f, 0.f, 0.f, 0.f};
            const bf16_t* ah = atH + (size_t)(wave * 16 + l15) * 2048;
            const bf16_t* al = atL + (size_t)(wave * 16 + l15) * 2048;
            #pragma unroll 8
            for (int kk = 0; kk < 64; ++kk) {
                bf16x8 avh = aload16(ah + kk * 32 + l4 * 8);
                bf16x8 avl = aload16(al + kk * 32 + l4 * 8);
                bf16x8 bvh = *(const bf16x8*)(sm + W3H_OFF + l15 * 4096 +
                                              ((kk * 64 + l4 * 16) ^ ((l15 & 7) << 4)));
                acc3 = __builtin_amdgcn_mfma_f32_16x16x32_bf16(avh, bvh, acc3, 0, 0, 0);
                acc3 = __builtin_amdgcn_mfma_f32_16x16x32_bf16(avl, bvh, acc3, 0, 0, 0);
            }
            #pragma unroll
            for (int r2 = 0; r2 < 4; ++r2) {
                float ir  = acc3[r2];
                float iz  = __shfl(acc3[r2], (lane & 48) | (l15 + 4), 64);
                float in2 = __shfl(acc3[r2], (lane & 48) | (l15 + 8), 64);
                float hr  = acc1[r2];
                float hz  = __shfl(acc1[r2], (lane & 48) | (l15 + 4), 64);
                float hn  = __shfl(acc1[r2], (lane & 48) | (l15 + 8), 64);
                float h2 = 0.f;
                int b = wave * 16 + l4 * 4 + r2;
                if (l15 < 4) {
                    float rr = sigm_(ir + bi2r + hr + bh2r);
                    float zz = sigm_(iz + bi2z + hz + bh2z);
                    float nn = tanh_(in2 + bi2n + rr * (hn + bh2n));
                    h2 = (1.f - zz) * nn + zz * h1r_[r2];
                    hf[b * 1024 + j] = h2;
                    outseq[((size_t)b * T_ + t) * 1024 + j] = h2;
                    if (t == T_ - 1) hfinal[b * 1024 + j] = h2;
                }
                float h2o = __shfl(h2, lane + 1, 64);
                if (l15 < 4 && (l15 & 1) == 0) {
                    bf16_t hS = (bf16_t)h2, hO = (bf16_t)h2o;
                    astore_pair(hbH + b * 1024 + j, hS, hO);
                    astore_pair(hbL + b * 1024 + j,
                                (bf16_t)(h2 - (float)hS), (bf16_t)(h2o - (float)hO));
                }
            }
        }
        gbar(flags, done, ++epoch, blk, tid);
    }
}

// ===================== final logits =====================
__global__ __launch_bounds__(256)
void final_kernel(const float* __restrict__ Lacc,
                  const float* __restrict__ bi, const float* __restrict__ bh,
                  const float* __restrict__ bc, float* __restrict__ out)
{
    int i = blockIdx.x * 256 + threadIdx.x;
    int e = i & 511;
    out[i] = tanh_(Lacc[i] + bi[e] + bh[e] + bc[e]);
}

// ===================== host =====================
extern "C" void kernel_launch(void* const* d_in, const int* in_sizes, int n_in,
                              void* d_out, int out_size, void* d_ws, size_t ws_size,
                              hipStream_t stream)
{
    const int*   y       = (const int*)  d_in[0];
    const float* context = (const float*)d_in[1];
    const int*   cmask   = (const int*)  d_in[2];
    const float* hidden  = (const float*)d_in[3];
    const float* emb     = (const float*)d_in[4];
    const float* W_ih1   = (const float*)d_in[5];
    const float* W_hh1   = (const float*)d_in[6];
    const float* b_ih1   = (const float*)d_in[7];
    const float* b_hh1   = (const float*)d_in[8];
    const float* Wq      = (const float*)d_in[9];
    const float* bq      = (const float*)d_in[10];
    const float* Wk      = (const float*)d_in[11];
    const float* v_attn  = (const float*)d_in[12];
    const float* W_ih2   = (const float*)d_in[13];
    const float* W_hh2   = (const float*)d_in[14];
    const float* b_ih2   = (const float*)d_in[15];
    const float* b_hh2   = (const float*)d_in[16];
    const float* Wi      = (const float*)d_in[17];
    const float* bi      = (const float*)d_in[18];
    const float* Wh      = (const float*)d_in[19];
    const float* bh      = (const float*)d_in[20];
    const float* Wc      = (const float*)d_in[21];
    const float* bc      = (const float*)d_in[22];

    char* ws = (char*)d_ws;
    size_t o = 0;
    auto alloc = [&](size_t bytes) { char* p = ws + o; o += (bytes + 255) & ~(size_t)255; return p; };
    unsigned* flags = (unsigned*)alloc(NBLK * FLSTR * 4);
    unsigned* done  = (unsigned*)alloc(8 * FLSTR * 4);
    float*  x       = (float*) alloc((size_t)2048 * 512 * 4);
    float*  WkT     = (float*) alloc((size_t)1024 * 2048 * 4);
    float*  WqT     = (float*) alloc((size_t)1024 * 1024 * 4);
    bf16_t* ctxb    = (bf16_t*)alloc((size_t)4096 * 2048 * 2);
    float*  Xg      = (float*) alloc((size_t)2048 * 3072 * 4);
    float*  Lacc    = (float*) alloc((size_t)2048 * 512 * 4);
    float*  cacheK  = (float*) alloc((size_t)4096 * 1024 * 4);
    float*  qg      = (float*) alloc((size_t)64 * 1024 * 4);
    float*  hf      = (float*) alloc((size_t)64 * 1024 * 4);
    bf16_t* hbH     = (bf16_t*)alloc((size_t)64 * 1024 * 2);
    bf16_t* hbL     = (bf16_t*)alloc((size_t)64 * 1024 * 2);
    bf16_t* h1H     = (bf16_t*)alloc((size_t)64 * 1024 * 2);
    bf16_t* h1L     = (bf16_t*)alloc((size_t)64 * 1024 * 2);
    bf16_t* atH     = (bf16_t*)alloc((size_t)64 * 2048 * 2);
    bf16_t* atL     = (bf16_t*)alloc((size_t)64 * 2048 * 2);
    float*  attnseq = (float*) alloc((size_t)2048 * 2048 * 4);
    float*  outseq  = (float*) alloc((size_t)2048 * 1024 * 4);
    float*  scg     = (float*) alloc((size_t)64 * 64 * 4);

    hipMemsetAsync(flags, 0, (NBLK * FLSTR + 8 * FLSTR) * 4, stream);

    embed_kernel<<<(B_*T_*E_/4 + 255)/256, 256, 0, stream>>>(y, emb, x);
    transpose_kernel<<<dim3(1024/32, 2048/32), dim3(32,32), 0, stream>>>(Wk, WkT, 2048, 1024);
    transpose_kernel<<<dim3(1024/32, 1024/32), dim3(32,32), 0, stream>>>(Wq, WqT, 1024, 1024);
    cvt_ctx<<<(4096*2048/8)/256, 256, 0, stream>>>(context, ctxb);

    sgemm<0><<<dim3(G_/128, 16), 256, 0, stream>>>(x, W_ih1, Xg, G_, E_);
    sgemm<0><<<dim3(E_/128, 16), 256, 0, stream>>>(x, Wi, Lacc, E_, E_);
    sgemm<0><<<dim3(H_/128, 32), 256, 0, stream>>>(context, WkT, cacheK, H_, C_);

    hipFuncSetAttribute((const void*)scan_kernel, hipFuncAttributeMaxDynamicSharedMemorySize, SMEM_BYTES);
    scan_kernel<<<NBLK, 1024, SMEM_BYTES, stream>>>(
        W_hh1, W_hh2, WqT, W_ih2, Xg,
        b_ih1, b_hh1, b_ih2, b_hh2, bq, v_attn, cmask, hidden, cacheK, ctxb,
        qg, hf, hbH, hbL, h1H, h1L, atH, atL, attnseq, outseq,
        (float*)d_out + (size_t)B_ * T_ * E_, scg, flags, done);

    sgemm<1><<<dim3(E_/128, 16), 256, 0, stream>>>(outseq, Wh, Lacc, E_, H_);
    sgemm<1><<<dim3(E_/128, 16), 256, 0, stream>>>(attnseq, Wc, Lacc, E_, C_);

    final_kernel<<<(B_*T_*E_)/256, 256, 0, stream>>>(Lacc, bi, bh, bc, (float*)d_out);
}

// Round 9
// 3423.222 us; speedup vs baseline: 10.5579x; 1.0884x over previous
//
#include <hip/hip_runtime.h>
#include <math.h>

#define B_ 64
#define T_ 32
#define S_ 64
#define E_ 512
#define H_ 1024
#define C_ 2048
#define G_ 3072
#define NBLK 256
#define FLSTR 16   // 16 uints = 64B padding per flag slot

typedef __bf16 bf16_t;
typedef bf16_t bf16x8 __attribute__((ext_vector_type(8)));
typedef float f32x4 __attribute__((ext_vector_type(4)));
typedef unsigned long long u64;

__device__ __forceinline__ float sigm_(float x) { return 1.f / (1.f + __expf(-x)); }
__device__ __forceinline__ float tanh_(float x) { return 1.f - 2.f / (__expf(2.f * x) + 1.f); }

// ---- bypass (coherence-point) store helpers; loads stay normal/cached ----
__device__ __forceinline__ unsigned short bits_(bf16_t x)
{
    union { bf16_t b; unsigned short u; } c; c.b = x; return c.u;
}
__device__ __forceinline__ void astore_pair(bf16_t* p, bf16_t lo, bf16_t hi)
{
    unsigned u = (unsigned)bits_(lo) | ((unsigned)bits_(hi) << 16);
    __hip_atomic_store((unsigned*)p, u, __ATOMIC_RELAXED, __HIP_MEMORY_SCOPE_AGENT);
}
__device__ __forceinline__ void astore_f32(float* p, float v)
{
    union { float f; unsigned u; } c; c.f = v;
    __hip_atomic_store((unsigned*)p, c.u, __ATOMIC_RELAXED, __HIP_MEMORY_SCOPE_AGENT);
}
__device__ __forceinline__ void astore_2f32(float* p, float a, float b)
{
    union { float f[2]; u64 u; } c; c.f[0] = a; c.f[1] = b;
    __hip_atomic_store((u64*)p, c.u, __ATOMIC_RELAXED, __HIP_MEMORY_SCOPE_AGENT);
}

// split 8 consecutive f32 into hi/lo bf16x8
__device__ __forceinline__ void split8(const float* __restrict__ p, bf16x8& h, bf16x8& l)
{
    float4 a = *(const float4*)p;
    float4 b = *(const float4*)(p + 4);
    float v[8] = {a.x, a.y, a.z, a.w, b.x, b.y, b.z, b.w};
    #pragma unroll
    for (int q = 0; q < 8; ++q) {
        h[q] = (bf16_t)v[q];
        l[q] = (bf16_t)(v[q] - (float)h[q]);
    }
}

// ===================== helpers =====================
__global__ __launch_bounds__(256)
void embed_kernel(const int* __restrict__ y, const float* __restrict__ emb,
                  float* __restrict__ x)
{
    int i = blockIdx.x * 256 + threadIdx.x;      // B*T*E/4
    int row = i / (E_ / 4);
    int e4  = i % (E_ / 4);
    const float4* src = (const float4*)(emb + (size_t)y[row] * E_);
    ((float4*)(x + (size_t)row * E_))[e4] = src[e4];
}

__global__ void transpose_kernel(const float* __restrict__ in, float* __restrict__ out,
                                 int R, int Ccols)
{
    __shared__ float t[32][33];
    int r0 = blockIdx.y * 32, c0 = blockIdx.x * 32;
    t[threadIdx.y][threadIdx.x] = in[(size_t)(r0 + threadIdx.y) * Ccols + c0 + threadIdx.x];
    __syncthreads();
    out[(size_t)(c0 + threadIdx.y) * R + r0 + threadIdx.x] = t[threadIdx.x][threadIdx.y];
}

__global__ __launch_bounds__(256)
void cvt_ctx(const float* __restrict__ in, bf16_t* __restrict__ out)
{
    int i = blockIdx.x * 256 + threadIdx.x;
    const float4* s4 = (const float4*)in + 2 * i;
    float4 a = s4[0], b = s4[1];
    bf16x8 o;
    o[0] = (bf16_t)a.x; o[1] = (bf16_t)a.y; o[2] = (bf16_t)a.z; o[3] = (bf16_t)a.w;
    o[4] = (bf16_t)b.x; o[5] = (bf16_t)b.y; o[6] = (bf16_t)b.z; o[7] = (bf16_t)b.w;
    ((bf16x8*)out)[i] = o;
}

// ============ split-precision GEMM: f32 A[M,K] @ f32 Wt[N,K]^T -> f32 =======
#define LSTR 80

template<int ACCUM>
__global__ __launch_bounds__(256)
void sgemm(const float* __restrict__ A, const float* __restrict__ Wt,
           float* __restrict__ out, int N, int K)
{
    __shared__ char AH[128 * LSTR];
    __shared__ char AL[128 * LSTR];
    __shared__ char WH[128 * LSTR];
    __shared__ char WL[128 * LSTR];
    const int tid = threadIdx.x;
    const int lane = tid & 63, wave = tid >> 6;
    const int m0 = blockIdx.y * 128, n0 = blockIdx.x * 128;
    const int wm = (wave & 1) * 64, wn = (wave >> 1) * 64;
    const int l15 = lane & 15, l4 = lane >> 4;

    f32x4 acc[4][4] = {};

    for (int k0 = 0; k0 < K; k0 += 32) {
        #pragma unroll
        for (int p = 0; p < 2; ++p) {
            int e = tid + p * 256;
            int row = e >> 2, ch = e & 3;
            int off = row * LSTR + ch * 16;
            bf16x8 h, l;
            split8(A + (size_t)(m0 + row) * K + k0 + ch * 8, h, l);
            *(bf16x8*)(AH + off) = h; *(bf16x8*)(AL + off) = l;
            split8(Wt + (size_t)(n0 + row) * K + k0 + ch * 8, h, l);
            *(bf16x8*)(WH + off) = h; *(bf16x8*)(WL + off) = l;
        }
        __syncthreads();
        bf16x8 ah[4], al[4], wh[4], wl[4];
        #pragma unroll
        for (int i = 0; i < 4; ++i) {
            int off = (wm + i * 16 + l15) * LSTR + l4 * 16;
            ah[i] = *(const bf16x8*)(AH + off);
            al[i] = *(const bf16x8*)(AL + off);
        }
        #pragma unroll
        for (int j = 0; j < 4; ++j) {
            int off = (wn + j * 16 + l15) * LSTR + l4 * 16;
            wh[j] = *(const bf16x8*)(WH + off);
            wl[j] = *(const bf16x8*)(WL + off);
        }
        #pragma unroll
        for (int i = 0; i < 4; ++i)
            #pragma unroll
            for (int j = 0; j < 4; ++j) {
                acc[i][j] = __builtin_amdgcn_mfma_f32_16x16x32_bf16(ah[i], wh[j], acc[i][j], 0, 0, 0);
                acc[i][j] = __builtin_amdgcn_mfma_f32_16x16x32_bf16(ah[i], wl[j], acc[i][j], 0, 0, 0);
                acc[i][j] = __builtin_amdgcn_mfma_f32_16x16x32_bf16(al[i], wh[j], acc[i][j], 0, 0, 0);
            }
        __syncthreads();
    }

    #pragma unroll
    for (int i = 0; i < 4; ++i)
        #pragma unroll
        for (int j = 0; j < 4; ++j)
            #pragma unroll
            for (int r = 0; r < 4; ++r) {
                int m = m0 + wm + i * 16 + l4 * 4 + r;
                int n = n0 + wn + j * 16 + l15;
                if (ACCUM) out[(size_t)m * N + n] += acc[i][j][r];
                else       out[(size_t)m * N + n]  = acc[i][j][r];
            }
}

// ===================== persistent scan kernel =====================
#define W1H_OFF 0         // W_hh1 hi : 12 rows x 2048B
#define W1L_OFF 24576     // W_hh1 lo : 12 rows
#define W3H_OFF 49152     // W_ih2 hi : 12 rows x 4096B
#define W2H_OFF 98304     // [W_hh2 gates; WqT] hi : 16 rows x 2048B
#define W2L_OFF 131072    // lo : 16 rows -> ends 163840
#define SMEM_BYTES 163840

// Fence-free barrier (flags are relaxed agent atomics; no L2 invalidation).
__device__ __forceinline__ void gbar(unsigned* flags, unsigned* done,
                                     unsigned epoch, int blk, int tid)
{
    asm volatile("s_waitcnt vmcnt(0)" ::: "memory");
    __syncthreads();
    if (blk == 0) {
        if (tid > 0 && tid < NBLK) {
            while (__hip_atomic_load(&flags[tid * FLSTR], __ATOMIC_RELAXED,
                                     __HIP_MEMORY_SCOPE_AGENT) < epoch)
                __builtin_amdgcn_s_sleep(4);
        }
        __syncthreads();
        if (tid < 8)
            __hip_atomic_store(&done[tid * FLSTR], epoch, __ATOMIC_RELAXED,
                               __HIP_MEMORY_SCOPE_AGENT);
        __syncthreads();
    } else {
        if (tid == 0) {
            __hip_atomic_store(&flags[blk * FLSTR], epoch, __ATOMIC_RELAXED,
                               __HIP_MEMORY_SCOPE_AGENT);
            while (__hip_atomic_load(&done[(blk & 7) * FLSTR], __ATOMIC_RELAXED,
                                     __HIP_MEMORY_SCOPE_AGENT) < epoch)
                __builtin_amdgcn_s_sleep(4);
        }
        __syncthreads();
    }
}

__global__ __launch_bounds__(1024, 1)
void scan_kernel(
    const float* __restrict__ Whh1, const float* __restrict__ Whh2,
    const float* __restrict__ WqT,  const float* __restrict__ Wih2,
    const float* __restrict__ Xg,
    const float* __restrict__ b_ih1, const float* __restrict__ b_hh1,
    const float* __restrict__ b_ih2, const float* __restrict__ b_hh2,
    const float* __restrict__ bq,    const float* __restrict__ v_attn,
    const int*   __restrict__ cmask,
    const float* __restrict__ hidden,
    const float* __restrict__ cacheK, const bf16_t* __restrict__ ctxb,
    float* __restrict__ qgv, float* __restrict__ hf,
    bf16_t* __restrict__ h1H, bf16_t* __restrict__ h1L,
    float* __restrict__ attnseq, float* __restrict__ outseq,
    float* __restrict__ hfinal,
    float* __restrict__ scgv,
    unsigned* __restrict__ flags, unsigned* __restrict__ done)
{
    extern __shared__ char sm[];
    const int tid = threadIdx.x, blk = blockIdx.x;
    const int lane = tid & 63, wave = tid >> 6;   // 16 waves
    const int l15 = lane & 15, l4 = lane >> 4;
    const int blk4 = blk * 4;
    const int ab  = blk & 63;    // attention batch
    const int aq  = blk >> 6;    // attention quarter (0..3)

    // One-time cache invalidate: drops any stale (poisoned / prev-replay)
    // lines so every versioned address is a guaranteed-fresh first touch.
    if (tid == 0) __builtin_amdgcn_fence(__ATOMIC_ACQUIRE, "agent");
    __syncthreads();

    // ---- stage weight slices into LDS as hi/lo bf16 (swizzled) ----
    for (int e = tid; e < 12 * 128; e += 1024) {           // W_hh1 (K=1024)
        int r = e >> 7, c = e & 127;
        bf16x8 h, l;
        split8(Whh1 + (size_t)((r >> 2) * 1024 + blk4 + (r & 3)) * 1024 + c * 8, h, l);
        int off = r * 2048 + ((c * 16) ^ ((r & 7) << 4));
        *(bf16x8*)(sm + W1H_OFF + off) = h;
        *(bf16x8*)(sm + W1L_OFF + off) = l;
    }
    for (int e = tid; e < 16 * 128; e += 1024) {           // [W_hh2 gates; WqT] (K=1024)
        int r = e >> 7, c = e & 127;
        const float* src = (r < 12)
            ? Whh2 + (size_t)((r >> 2) * 1024 + blk4 + (r & 3)) * 1024 + c * 8
            : WqT + (size_t)(blk4 + r - 12) * 1024 + c * 8;
        bf16x8 h, l;
        split8(src, h, l);
        int off = r * 2048 + ((c * 16) ^ ((r & 7) << 4));
        *(bf16x8*)(sm + W2H_OFF + off) = h;
        *(bf16x8*)(sm + W2L_OFF + off) = l;
    }
    for (int e = tid; e < 12 * 256; e += 1024) {           // W_ih2 hi only (K=2048)
        int r = e >> 8, c = e & 255;
        bf16x8 h, l;
        split8(Wih2 + (size_t)((r >> 2) * 1024 + blk4 + (r & 3)) * 2048 + c * 8, h, l);
        *(bf16x8*)(sm + W3H_OFF + r * 4096 + ((c * 16) ^ ((r & 7) << 4))) = h;
    }

    // hf init (thread-private recurrent f32 state)
    const int j = blk4 + l15;
    if (wave < 4 && l15 < 4) {
        #pragma unroll
        for (int r2 = 0; r2 < 4; ++r2) {
            int b = wave * 16 + l4 * 4 + r2;
            hf[b * 1024 + j] = hidden[b * 1024 + j];
        }
    }

    // attention constants in registers
    float vreg[16], bqreg[16];
    #pragma unroll
    for (int i = 0; i < 16; ++i) {
        vreg[i]  = v_attn[lane + 64 * i];
        bqreg[i] = bq[lane + 64 * i];
    }

    // per-thread GRU biases
    float bi1r = 0, bi1z = 0, bi1n = 0, bh1r = 0, bh1z = 0, bh1n = 0;
    float bi2r = 0, bi2z = 0, bi2n = 0, bh2r = 0, bh2z = 0, bh2n = 0;
    if (wave < 4 && l15 < 4) {
        bi1r = b_ih1[j]; bi1z = b_ih1[1024 + j]; bi1n = b_ih1[2048 + j];
        bh1r = b_hh1[j]; bh1z = b_hh1[1024 + j]; bh1n = b_hh1[2048 + j];
        bi2r = b_ih2[j]; bi2z = b_ih2[1024 + j]; bi2n = b_ih2[2048 + j];
        bh2r = b_hh2[j]; bh2z = b_hh2[1024 + j]; bh2n = b_hh2[2048 + j];
    }

    unsigned epoch = 0;
    gbar(flags, done, ++epoch, blk, tid);

    float h1r_[4] = {0.f, 0.f, 0.f, 0.f};
    f32x4 acc1 = {0.f, 0.f, 0.f, 0.f};

    for (int t = 0; t < T_; ++t) {
        // ===== P0: gh1 = h @ W_hh1^T (split 3-term) + in-register GRU1 =====
        if (wave < 4) {
            f32x4 acc0 = {0.f, 0.f, 0.f, 0.f};
            const int brow = wave * 16 + l15;
            // h source: versioned f32 (outseq row t-1, or hidden at t=0); cached read
            const float* asrc = (t == 0) ? hidden + (size_t)brow * 1024
                                         : outseq + ((size_t)brow * T_ + t - 1) * 1024;
            #pragma unroll 8
            for (int kk = 0; kk < 32; ++kk) {
                bf16x8 avh, avl;
                split8(asrc + kk * 32 + l4 * 8, avh, avl);
                int boff = (kk * 64 + l4 * 16) ^ ((l15 & 7) << 4);
                bf16x8 bvh = *(const bf16x8*)(sm + W1H_OFF + l15 * 2048 + boff);
                bf16x8 bvl = *(const bf16x8*)(sm + W1L_OFF + l15 * 2048 + boff);
                acc0 = __builtin_amdgcn_mfma_f32_16x16x32_bf16(avh, bvh, acc0, 0, 0, 0);
                acc0 = __builtin_amdgcn_mfma_f32_16x16x32_bf16(avl, bvh, acc0, 0, 0, 0);
                acc0 = __builtin_amdgcn_mfma_f32_16x16x32_bf16(avh, bvl, acc0, 0, 0, 0);
            }
            #pragma unroll
            for (int r2 = 0; r2 < 4; ++r2) {
                float gr = acc0[r2];
                float gz = __shfl(acc0[r2], (lane & 48) | (l15 + 4), 64);
                float gn = __shfl(acc0[r2], (lane & 48) | (l15 + 8), 64);
                float h1v = 0.f;
                int b = wave * 16 + l4 * 4 + r2;
                if (l15 < 4) {
                    const float* xg = Xg + ((size_t)b * T_ + t) * 3072;
                    float rr = sigm_(xg[j]          + bi1r + gr + bh1r);
                    float zz = sigm_(xg[1024 + j]   + bi1z + gz + bh1z);
                    float nn = tanh_(xg[2048 + j]   + bi1n + rr * (gn + bh1n));
                    h1v = (1.f - zz) * nn + zz * hf[b * 1024 + j];
                    h1r_[r2] = h1v;
                }
                float h1o = __shfl(h1v, lane + 1, 64);
                if (l15 < 4 && (l15 & 1) == 0) {
                    bf16_t hS = (bf16_t)h1v, hO = (bf16_t)h1o;
                    size_t vo = ((size_t)t * 64 + b) * 1024 + j;
                    astore_pair(h1H + vo, hS, hO);
                    astore_pair(h1L + vo,
                                (bf16_t)(h1v - (float)hS), (bf16_t)(h1o - (float)hO));
                }
            }
        }
        gbar(flags, done, ++epoch, blk, tid);

        // ===== P1: [gh2 | q] = h1 @ [W_hh2 ; WqT]^T (split 3-term) =====
        if (wave < 4) {
            acc1 = (f32x4){0.f, 0.f, 0.f, 0.f};
            const int brow = wave * 16 + l15;
            const bf16_t* ah = h1H + ((size_t)t * 64 + brow) * 1024;   // cached read
            const bf16_t* al = h1L + ((size_t)t * 64 + brow) * 1024;
            #pragma unroll 8
            for (int kk = 0; kk < 32; ++kk) {
                bf16x8 avh = *(const bf16x8*)(ah + kk * 32 + l4 * 8);
                bf16x8 avl = *(const bf16x8*)(al + kk * 32 + l4 * 8);
                int boff = (kk * 64 + l4 * 16) ^ ((l15 & 7) << 4);
                bf16x8 bvh = *(const bf16x8*)(sm + W2H_OFF + l15 * 2048 + boff);
                bf16x8 bvl = *(const bf16x8*)(sm + W2L_OFF + l15 * 2048 + boff);
                acc1 = __builtin_amdgcn_mfma_f32_16x16x32_bf16(avh, bvh, acc1, 0, 0, 0);
                acc1 = __builtin_amdgcn_mfma_f32_16x16x32_bf16(avl, bvh, acc1, 0, 0, 0);
                acc1 = __builtin_amdgcn_mfma_f32_16x16x32_bf16(avh, bvl, acc1, 0, 0, 0);
            }
            if (l15 >= 12) {
                int jq = blk4 + l15 - 12;
                #pragma unroll
                for (int r2 = 0; r2 < 4; ++r2)
                    astore_f32(&qgv[((size_t)t * 64 + (wave * 16 + l4 * 4 + r2)) * 1024 + jq],
                               acc1[r2]);
            }
        }
        gbar(flags, done, ++epoch, blk, tid);

        // ===== P2a: scores (batch ab, quarter aq; one s per wave) =====
        {
            int s = aq * 16 + wave;
            const float* qrow = qgv + ((size_t)t * 64 + ab) * 1024;    // cached read
            const float* ck = cacheK + ((size_t)ab * 64 + s) * 1024;
            float sum = 0.f;
            #pragma unroll
            for (int i = 0; i < 16; ++i)
                sum += tanh_(qrow[lane + 64 * i] + bqreg[i] + ck[lane + 64 * i]) * vreg[i];
            #pragma unroll
            for (int off = 32; off; off >>= 1) sum += __shfl_down(sum, off, 64);
            if (lane == 0) astore_f32(&scgv[(size_t)t * 4096 + ab * 64 + s], sum);
        }
        gbar(flags, done, ++epoch, blk, tid);

        // ===== P2b: softmax + PV (block covers 512 cols = quarter aq) =====
        if (tid < 256) {
            const float* scrow = scgv + (size_t)t * 4096 + ab * 64;    // cached read
            float v = (cmask[ab * 64 + lane] != 0) ? -3.4e38f : scrow[lane];
            float mx = v;
            #pragma unroll
            for (int off = 32; off; off >>= 1) mx = fmaxf(mx, __shfl_xor(mx, off, 64));
            float e = __expf(v - mx);
            float sden = e;
            #pragma unroll
            for (int off = 32; off; off >>= 1) sden += __shfl_xor(sden, off, 64);
            float prv = e / sden;

            int c = aq * 512 + tid * 2;
            const bf16_t* cb = ctxb + (size_t)ab * 64 * 2048 + c;
            float sum0 = 0.f, sum1 = 0.f;
            #pragma unroll 8
            for (int s = 0; s < 64; ++s) {
                float p = __shfl(prv, s, 64);
                bf16_t v0 = cb[(size_t)s * 2048];
                bf16_t v1 = cb[(size_t)s * 2048 + 1];
                sum0 += p * (float)v0;
                sum1 += p * (float)v1;
            }
            astore_2f32(attnseq + ((size_t)ab * T_ + t) * 2048 + c, sum0, sum1);
        }
        gbar(flags, done, ++epoch, blk, tid);

        // ===== P3: gi2 = attn @ W_ih2^T (A split, W hi) + GRU2 =====
        if (wave < 4) {
            f32x4 acc3 = {0.f, 0.f, 0.f, 0.f};
            const int brow = wave * 16 + l15;
            const float* aptr = attnseq + ((size_t)brow * T_ + t) * 2048;  // cached read
            #pragma unroll 8
            for (int kk = 0; kk < 64; ++kk) {
                bf16x8 avh, avl;
                split8(aptr + kk * 32 + l4 * 8, avh, avl);
                bf16x8 bvh = *(const bf16x8*)(sm + W3H_OFF + l15 * 4096 +
                                              ((kk * 64 + l4 * 16) ^ ((l15 & 7) << 4)));
                acc3 = __builtin_amdgcn_mfma_f32_16x16x32_bf16(avh, bvh, acc3, 0, 0, 0);
                acc3 = __builtin_amdgcn_mfma_f32_16x16x32_bf16(avl, bvh, acc3, 0, 0, 0);
            }
            #pragma unroll
            for (int r2 = 0; r2 < 4; ++r2) {
                float ir  = acc3[r2];
                float iz  = __shfl(acc3[r2], (lane & 48) | (l15 + 4), 64);
                float in2 = __shfl(acc3[r2], (lane & 48) | (l15 + 8), 64);
                float hr  = acc1[r2];
                float hz  = __shfl(acc1[r2], (lane & 48) | (l15 + 4), 64);
                float hn  = __shfl(acc1[r2], (lane & 48) | (l15 + 8), 64);
                int b = wave * 16 + l4 * 4 + r2;
                if (l15 < 4) {
                    float rr = sigm_(ir + bi2r + hr + bh2r);
                    float zz = sigm_(iz + bi2z + hz + bh2z);
                    float nn = tanh_(in2 + bi2n + rr * (hn + bh2n));
                    float h2 = (1.f - zz) * nn + zz * h1r_[r2];
                    hf[b * 1024 + j] = h2;
                    astore_f32(&outseq[((size_t)b * T_ + t) * 1024 + j], h2);
                    if (t == T_ - 1) hfinal[b * 1024 + j] = h2;
                }
            }
        }
        gbar(flags, done, ++epoch, blk, tid);
    }
}

// ===================== final logits =====================
__global__ __launch_bounds__(256)
void final_kernel(const float* __restrict__ Lacc,
                  const float* __restrict__ bi, const float* __restrict__ bh,
                  const float* __restrict__ bc, float* __restrict__ out)
{
    int i = blockIdx.x * 256 + threadIdx.x;
    int e = i & 511;
    out[i] = tanh_(Lacc[i] + bi[e] + bh[e] + bc[e]);
}

// ===================== host =====================
extern "C" void kernel_launch(void* const* d_in, const int* in_sizes, int n_in,
                              void* d_out, int out_size, void* d_ws, size_t ws_size,
                              hipStream_t stream)
{
    const int*   y       = (const int*)  d_in[0];
    const float* context = (const float*)d_in[1];
    const int*   cmask   = (const int*)  d_in[2];
    const float* hidden  = (const float*)d_in[3];
    const float* emb     = (const float*)d_in[4];
    const float* W_ih1   = (const float*)d_in[5];
    const float* W_hh1   = (const float*)d_in[6];
    const float* b_ih1   = (const float*)d_in[7];
    const float* b_hh1   = (const float*)d_in[8];
    const float* Wq      = (const float*)d_in[9];
    const float* bq      = (const float*)d_in[10];
    const float* Wk      = (const float*)d_in[11];
    const float* v_attn  = (const float*)d_in[12];
    const float* W_ih2   = (const float*)d_in[13];
    const float* W_hh2   = (const float*)d_in[14];
    const float* b_ih2   = (const float*)d_in[15];
    const float* b_hh2   = (const float*)d_in[16];
    const float* Wi      = (const float*)d_in[17];
    const float* bi      = (const float*)d_in[18];
    const float* Wh      = (const float*)d_in[19];
    const float* bh      = (const float*)d_in[20];
    const float* Wc      = (const float*)d_in[21];
    const float* bc      = (const float*)d_in[22];

    char* ws = (char*)d_ws;
    size_t o = 0;
    auto alloc = [&](size_t bytes) { char* p = ws + o; o += (bytes + 255) & ~(size_t)255; return p; };
    unsigned* flags = (unsigned*)alloc(NBLK * FLSTR * 4);
    unsigned* done  = (unsigned*)alloc(8 * FLSTR * 4);
    float*  x       = (float*) alloc((size_t)2048 * 512 * 4);
    float*  WkT     = (float*) alloc((size_t)1024 * 2048 * 4);
    float*  WqT     = (float*) alloc((size_t)1024 * 1024 * 4);
    bf16_t* ctxb    = (bf16_t*)alloc((size_t)4096 * 2048 * 2);
    float*  Xg      = (float*) alloc((size_t)2048 * 3072 * 4);
    float*  Lacc    = (float*) alloc((size_t)2048 * 512 * 4);
    float*  cacheK  = (float*) alloc((size_t)4096 * 1024 * 4);
    float*  qgv     = (float*) alloc((size_t)T_ * 64 * 1024 * 4);      // 8 MB, versioned
    float*  hf      = (float*) alloc((size_t)64 * 1024 * 4);
    bf16_t* h1H     = (bf16_t*)alloc((size_t)T_ * 64 * 1024 * 2);      // 4 MB, versioned
    bf16_t* h1L     = (bf16_t*)alloc((size_t)T_ * 64 * 1024 * 2);
    float*  attnseq = (float*) alloc((size_t)2048 * 2048 * 4);         // [B][T][C], versioned
    float*  outseq  = (float*) alloc((size_t)2048 * 1024 * 4);         // [B][T][H], versioned
    float*  scgv    = (float*) alloc((size_t)T_ * 64 * 64 * 4);        // versioned

    hipMemsetAsync(flags, 0, (NBLK * FLSTR + 8 * FLSTR) * 4, stream);

    embed_kernel<<<(B_*T_*E_/4 + 255)/256, 256, 0, stream>>>(y, emb, x);
    transpose_kernel<<<dim3(1024/32, 2048/32), dim3(32,32), 0, stream>>>(Wk, WkT, 2048, 1024);
    transpose_kernel<<<dim3(1024/32, 1024/32), dim3(32,32), 0, stream>>>(Wq, WqT, 1024, 1024);
    cvt_ctx<<<(4096*2048/8)/256, 256, 0, stream>>>(context, ctxb);

    sgemm<0><<<dim3(G_/128, 16), 256, 0, stream>>>(x, W_ih1, Xg, G_, E_);
    sgemm<0><<<dim3(E_/128, 16), 256, 0, stream>>>(x, Wi, Lacc, E_, E_);
    sgemm<0><<<dim3(H_/128, 32), 256, 0, stream>>>(context, WkT, cacheK, H_, C_);

    hipFuncSetAttribute((const void*)scan_kernel, hipFuncAttributeMaxDynamicSharedMemorySize, SMEM_BYTES);
    scan_kernel<<<NBLK, 1024, SMEM_BYTES, stream>>>(
        W_hh1, W_hh2, WqT, W_ih2, Xg,
        b_ih1, b_hh1, b_ih2, b_hh2, bq, v_attn, cmask, hidden, cacheK, ctxb,
        qgv, hf, h1H, h1L, attnseq, outseq,
        (float*)d_out + (size_t)B_ * T_ * E_, scgv, flags, done);

    sgemm<1><<<dim3(E_/128, 16), 256, 0, stream>>>(outseq, Wh, Lacc, E_, H_);
    sgemm<1><<<dim3(E_/128, 16), 256, 0, stream>>>(attnseq, Wc, Lacc, E_, C_);

    final_kernel<<<(B_*T_*E_)/256, 256, 0, stream>>>(Lacc, bi, bh, bc, (float*)d_out);
}

// Round 10
// 3133.699 us; speedup vs baseline: 11.5333x; 1.0924x over previous
//
#include <hip/hip_runtime.h>
#include <math.h>

#define B_ 64
#define T_ 32
#define S_ 64
#define E_ 512
#define H_ 1024
#define C_ 2048
#define G_ 3072
#define NBLK 256
#define FLSTR 16   // 16 uints = 64B padding per flag slot

typedef __bf16 bf16_t;
typedef bf16_t bf16x8 __attribute__((ext_vector_type(8)));
typedef float f32x4 __attribute__((ext_vector_type(4)));
typedef unsigned long long u64;

__device__ __forceinline__ float sigm_(float x) { return 1.f / (1.f + __expf(-x)); }
__device__ __forceinline__ float tanh_(float x) { return 1.f - 2.f / (__expf(2.f * x) + 1.f); }

// ---- bypass (coherence-point) store helpers; loads stay normal/cached ----
__device__ __forceinline__ unsigned short bits_(bf16_t x)
{
    union { bf16_t b; unsigned short u; } c; c.b = x; return c.u;
}
__device__ __forceinline__ void astore_pair(bf16_t* p, bf16_t lo, bf16_t hi)
{
    unsigned u = (unsigned)bits_(lo) | ((unsigned)bits_(hi) << 16);
    __hip_atomic_store((unsigned*)p, u, __ATOMIC_RELAXED, __HIP_MEMORY_SCOPE_AGENT);
}
__device__ __forceinline__ void astore_f32(float* p, float v)
{
    union { float f; unsigned u; } c; c.f = v;
    __hip_atomic_store((unsigned*)p, c.u, __ATOMIC_RELAXED, __HIP_MEMORY_SCOPE_AGENT);
}

// split 8 consecutive f32 into hi/lo bf16x8
__device__ __forceinline__ void split8(const float* __restrict__ p, bf16x8& h, bf16x8& l)
{
    float4 a = *(const float4*)p;
    float4 b = *(const float4*)(p + 4);
    float v[8] = {a.x, a.y, a.z, a.w, b.x, b.y, b.z, b.w};
    #pragma unroll
    for (int q = 0; q < 8; ++q) {
        h[q] = (bf16_t)v[q];
        l[q] = (bf16_t)(v[q] - (float)h[q]);
    }
}

// ===================== helpers =====================
__global__ __launch_bounds__(256)
void embed_kernel(const int* __restrict__ y, const float* __restrict__ emb,
                  float* __restrict__ x)
{
    int i = blockIdx.x * 256 + threadIdx.x;      // B*T*E/4
    int row = i / (E_ / 4);
    int e4  = i % (E_ / 4);
    const float4* src = (const float4*)(emb + (size_t)y[row] * E_);
    ((float4*)(x + (size_t)row * E_))[e4] = src[e4];
}

__global__ void transpose_kernel(const float* __restrict__ in, float* __restrict__ out,
                                 int R, int Ccols)
{
    __shared__ float t[32][33];
    int r0 = blockIdx.y * 32, c0 = blockIdx.x * 32;
    t[threadIdx.y][threadIdx.x] = in[(size_t)(r0 + threadIdx.y) * Ccols + c0 + threadIdx.x];
    __syncthreads();
    out[(size_t)(c0 + threadIdx.y) * R + r0 + threadIdx.x] = t[threadIdx.x][threadIdx.y];
}

__global__ __launch_bounds__(256)
void cvt_ctx(const float* __restrict__ in, bf16_t* __restrict__ out)
{
    int i = blockIdx.x * 256 + threadIdx.x;
    const float4* s4 = (const float4*)in + 2 * i;
    float4 a = s4[0], b = s4[1];
    bf16x8 o;
    o[0] = (bf16_t)a.x; o[1] = (bf16_t)a.y; o[2] = (bf16_t)a.z; o[3] = (bf16_t)a.w;
    o[4] = (bf16_t)b.x; o[5] = (bf16_t)b.y; o[6] = (bf16_t)b.z; o[7] = (bf16_t)b.w;
    ((bf16x8*)out)[i] = o;
}

// ============ split-precision GEMM: f32 A[M,K] @ f32 Wt[N,K]^T -> f32 =======
// PERM=1: write into xg2 layout [j>>2][t][b][gate*4 + (j&3)]  (m = b*32+t, n = gate*1024+j)
#define LSTR 80

template<int ACCUM, int PERM>
__global__ __launch_bounds__(256)
void sgemm(const float* __restrict__ A, const float* __restrict__ Wt,
           float* __restrict__ out, int N, int K)
{
    __shared__ char AH[128 * LSTR];
    __shared__ char AL[128 * LSTR];
    __shared__ char WH[128 * LSTR];
    __shared__ char WL[128 * LSTR];
    const int tid = threadIdx.x;
    const int lane = tid & 63, wave = tid >> 6;
    const int m0 = blockIdx.y * 128, n0 = blockIdx.x * 128;
    const int wm = (wave & 1) * 64, wn = (wave >> 1) * 64;
    const int l15 = lane & 15, l4 = lane >> 4;

    f32x4 acc[4][4] = {};

    for (int k0 = 0; k0 < K; k0 += 32) {
        #pragma unroll
        for (int p = 0; p < 2; ++p) {
            int e = tid + p * 256;
            int row = e >> 2, ch = e & 3;
            int off = row * LSTR + ch * 16;
            bf16x8 h, l;
            split8(A + (size_t)(m0 + row) * K + k0 + ch * 8, h, l);
            *(bf16x8*)(AH + off) = h; *(bf16x8*)(AL + off) = l;
            split8(Wt + (size_t)(n0 + row) * K + k0 + ch * 8, h, l);
            *(bf16x8*)(WH + off) = h; *(bf16x8*)(WL + off) = l;
        }
        __syncthreads();
        bf16x8 ah[4], al[4], wh[4], wl[4];
        #pragma unroll
        for (int i = 0; i < 4; ++i) {
            int off = (wm + i * 16 + l15) * LSTR + l4 * 16;
            ah[i] = *(const bf16x8*)(AH + off);
            al[i] = *(const bf16x8*)(AL + off);
        }
        #pragma unroll
        for (int j = 0; j < 4; ++j) {
            int off = (wn + j * 16 + l15) * LSTR + l4 * 16;
            wh[j] = *(const bf16x8*)(WH + off);
            wl[j] = *(const bf16x8*)(WL + off);
        }
        #pragma unroll
        for (int i = 0; i < 4; ++i)
            #pragma unroll
            for (int j = 0; j < 4; ++j) {
                acc[i][j] = __builtin_amdgcn_mfma_f32_16x16x32_bf16(ah[i], wh[j], acc[i][j], 0, 0, 0);
                acc[i][j] = __builtin_amdgcn_mfma_f32_16x16x32_bf16(ah[i], wl[j], acc[i][j], 0, 0, 0);
                acc[i][j] = __builtin_amdgcn_mfma_f32_16x16x32_bf16(al[i], wh[j], acc[i][j], 0, 0, 0);
            }
        __syncthreads();
    }

    #pragma unroll
    for (int i = 0; i < 4; ++i)
        #pragma unroll
        for (int j = 0; j < 4; ++j)
            #pragma unroll
            for (int r = 0; r < 4; ++r) {
                int m = m0 + wm + i * 16 + l4 * 4 + r;
                int n = n0 + wn + j * 16 + l15;
                if (PERM) {
                    int b = m >> 5, t = m & 31;
                    int gate = n >> 10, jj = n & 1023;
                    size_t dst = (((size_t)(jj >> 2) * 32 + t) * 64 + b) * 12
                                 + gate * 4 + (jj & 3);
                    out[dst] = acc[i][j][r];
                } else if (ACCUM) {
                    out[(size_t)m * N + n] += acc[i][j][r];
                } else {
                    out[(size_t)m * N + n] = acc[i][j][r];
                }
            }
}

// ===================== persistent scan kernel =====================
#define W1H_OFF 0         // W_hh1 hi : 12 rows x 2048B
#define W1L_OFF 24576     // W_hh1 lo : 12 rows
#define W3H_OFF 49152     // W_ih2 hi : 12 rows x 4096B
#define W2H_OFF 98304     // [W_hh2 gates; WqT] hi : 16 rows x 2048B
#define W2L_OFF 131072    // lo : 16 rows -> ends 163840
#define SMEM_BYTES 163840

// Fence-free barrier (flags are relaxed agent atomics; no L2 invalidation).
__device__ __forceinline__ void gbar(unsigned* flags, unsigned* done,
                                     unsigned epoch, int blk, int tid)
{
    asm volatile("s_waitcnt vmcnt(0)" ::: "memory");
    __syncthreads();
    if (blk == 0) {
        if (tid > 0 && tid < NBLK) {
            while (__hip_atomic_load(&flags[tid * FLSTR], __ATOMIC_RELAXED,
                                     __HIP_MEMORY_SCOPE_AGENT) < epoch)
                __builtin_amdgcn_s_sleep(4);
        }
        __syncthreads();
        if (tid < 8)
            __hip_atomic_store(&done[tid * FLSTR], epoch, __ATOMIC_RELAXED,
                               __HIP_MEMORY_SCOPE_AGENT);
        __syncthreads();
    } else {
        if (tid == 0) {
            __hip_atomic_store(&flags[blk * FLSTR], epoch, __ATOMIC_RELAXED,
                               __HIP_MEMORY_SCOPE_AGENT);
            while (__hip_atomic_load(&done[(blk & 7) * FLSTR], __ATOMIC_RELAXED,
                                     __HIP_MEMORY_SCOPE_AGENT) < epoch)
                __builtin_amdgcn_s_sleep(4);
        }
        __syncthreads();
    }
}

__global__ __launch_bounds__(1024, 4)
void scan_kernel(
    const float* __restrict__ Whh1, const float* __restrict__ Whh2,
    const float* __restrict__ WqT,  const float* __restrict__ Wih2,
    const float* __restrict__ xg2,
    const float* __restrict__ b_ih1, const float* __restrict__ b_hh1,
    const float* __restrict__ b_ih2, const float* __restrict__ b_hh2,
    const float* __restrict__ bq,    const float* __restrict__ v_attn,
    const int*   __restrict__ cmask,
    const float* __restrict__ hidden,
    const float* __restrict__ cacheK, const bf16_t* __restrict__ ctxb,
    float* __restrict__ qgv, float* __restrict__ hf,
    bf16_t* __restrict__ h1H, bf16_t* __restrict__ h1L,
    float* __restrict__ attnseq, float* __restrict__ outseq,
    float* __restrict__ hfinal,
    float* __restrict__ scgv,
    unsigned* __restrict__ flags, unsigned* __restrict__ done)
{
    extern __shared__ char sm[];
    const int tid = threadIdx.x, blk = blockIdx.x;
    const int lane = tid & 63, wave = tid >> 6;   // 16 waves
    const int l15 = lane & 15, l4 = lane >> 4;
    const int blk4 = blk * 4;
    const int ab  = blk & 63;    // attention batch
    const int aq  = blk >> 6;    // attention quarter (0..3)

    // One-time cache invalidate (stale poisoned lines), then only fresh data.
    if (tid == 0) __builtin_amdgcn_fence(__ATOMIC_ACQUIRE, "agent");
    __syncthreads();

    // ---- stage weight slices into LDS as hi/lo bf16 (swizzled) ----
    for (int e = tid; e < 12 * 128; e += 1024) {           // W_hh1 (K=1024)
        int r = e >> 7, c = e & 127;
        bf16x8 h, l;
        split8(Whh1 + (size_t)((r >> 2) * 1024 + blk4 + (r & 3)) * 1024 + c * 8, h, l);
        int off = r * 2048 + ((c * 16) ^ ((r & 7) << 4));
        *(bf16x8*)(sm + W1H_OFF + off) = h;
        *(bf16x8*)(sm + W1L_OFF + off) = l;
    }
    for (int e = tid; e < 16 * 128; e += 1024) {           // [W_hh2 gates; WqT] (K=1024)
        int r = e >> 7, c = e & 127;
        const float* src = (r < 12)
            ? Whh2 + (size_t)((r >> 2) * 1024 + blk4 + (r & 3)) * 1024 + c * 8
            : WqT + (size_t)(blk4 + r - 12) * 1024 + c * 8;
        bf16x8 h, l;
        split8(src, h, l);
        int off = r * 2048 + ((c * 16) ^ ((r & 7) << 4));
        *(bf16x8*)(sm + W2H_OFF + off) = h;
        *(bf16x8*)(sm + W2L_OFF + off) = l;
    }
    for (int e = tid; e < 12 * 256; e += 1024) {           // W_ih2 hi only (K=2048)
        int r = e >> 8, c = e & 255;
        bf16x8 h, l;
        split8(Wih2 + (size_t)((r >> 2) * 1024 + blk4 + (r & 3)) * 2048 + c * 8, h, l);
        *(bf16x8*)(sm + W3H_OFF + r * 4096 + ((c * 16) ^ ((r & 7) << 4))) = h;
    }

    // hf init (thread-private recurrent f32 state)
    const int j = blk4 + l15;
    if (wave < 4 && l15 < 4) {
        #pragma unroll
        for (int r2 = 0; r2 < 4; ++r2) {
            int b = wave * 16 + l4 * 4 + r2;
            hf[b * 1024 + j] = hidden[b * 1024 + j];
        }
    }

    // ---- attention data pinned in REGISTERS (time-invariant) ----
    float vreg[16], bqreg[16];
    #pragma unroll
    for (int i = 0; i < 16; ++i) {
        vreg[i]  = v_attn[lane + 64 * i];
        bqreg[i] = bq[lane + 64 * i];
    }
    // cacheK row s = aq*16+wave, lane holds ck[lane + 64*i]
    float ckreg[16];
    {
        const float* ck = cacheK + ((size_t)ab * 64 + aq * 16 + wave) * 1024;
        #pragma unroll
        for (int i = 0; i < 16; ++i) ckreg[i] = ck[lane + 64 * i];
    }
    // ctx column cmy = aq*512 + tid/2; this thread covers s = sbase..sbase+31
    const int cmy = aq * 512 + (tid >> 1);
    const int sbase = (tid & 1) * 32;
    unsigned cr[16];
    {
        const bf16_t* cb = ctxb + ((size_t)ab * 64 + sbase) * 2048 + cmy;
        #pragma unroll
        for (int q = 0; q < 16; ++q) {
            unsigned lo = bits_(cb[(size_t)(2 * q) * 2048]);
            unsigned hi = bits_(cb[(size_t)(2 * q + 1) * 2048]);
            cr[q] = lo | (hi << 16);
        }
    }

    // per-thread GRU biases
    float bi1r = 0, bi1z = 0, bi1n = 0, bh1r = 0, bh1z = 0, bh1n = 0;
    float bi2r = 0, bi2z = 0, bi2n = 0, bh2r = 0, bh2z = 0, bh2n = 0;
    if (wave < 4 && l15 < 4) {
        bi1r = b_ih1[j]; bi1z = b_ih1[1024 + j]; bi1n = b_ih1[2048 + j];
        bh1r = b_hh1[j]; bh1z = b_hh1[1024 + j]; bh1n = b_hh1[2048 + j];
        bi2r = b_ih2[j]; bi2z = b_ih2[1024 + j]; bi2n = b_ih2[2048 + j];
        bh2r = b_hh2[j]; bh2z = b_hh2[1024 + j]; bh2n = b_hh2[2048 + j];
    }

    unsigned epoch = 0;
    gbar(flags, done, ++epoch, blk, tid);

    float h1r_[4] = {0.f, 0.f, 0.f, 0.f};
    f32x4 acc1 = {0.f, 0.f, 0.f, 0.f};

    for (int t = 0; t < T_; ++t) {
        // ===== P0: gh1 = h @ W_hh1^T (split 3-term) + in-register GRU1 =====
        if (wave < 4) {
            f32x4 acc0 = {0.f, 0.f, 0.f, 0.f};
            const int brow = wave * 16 + l15;
            const float* asrc = (t == 0) ? hidden + (size_t)brow * 1024
                                         : outseq + ((size_t)brow * T_ + t - 1) * 1024;
            #pragma unroll 8
            for (int kk = 0; kk < 32; ++kk) {
                bf16x8 avh, avl;
                split8(asrc + kk * 32 + l4 * 8, avh, avl);
                int boff = (kk * 64 + l4 * 16) ^ ((l15 & 7) << 4);
                bf16x8 bvh = *(const bf16x8*)(sm + W1H_OFF + l15 * 2048 + boff);
                bf16x8 bvl = *(const bf16x8*)(sm + W1L_OFF + l15 * 2048 + boff);
                acc0 = __builtin_amdgcn_mfma_f32_16x16x32_bf16(avh, bvh, acc0, 0, 0, 0);
                acc0 = __builtin_amdgcn_mfma_f32_16x16x32_bf16(avl, bvh, acc0, 0, 0, 0);
                acc0 = __builtin_amdgcn_mfma_f32_16x16x32_bf16(avh, bvl, acc0, 0, 0, 0);
            }
            const float* xg = xg2 + (((size_t)blk * 32 + t) * 64) * 12;
            #pragma unroll
            for (int r2 = 0; r2 < 4; ++r2) {
                float gr = acc0[r2];
                float gz = __shfl(acc0[r2], (lane & 48) | (l15 + 4), 64);
                float gn = __shfl(acc0[r2], (lane & 48) | (l15 + 8), 64);
                float h1v = 0.f;
                int b = wave * 16 + l4 * 4 + r2;
                if (l15 < 4) {
                    float rr = sigm_(xg[b * 12 + l15]     + bi1r + gr + bh1r);
                    float zz = sigm_(xg[b * 12 + 4 + l15] + bi1z + gz + bh1z);
                    float nn = tanh_(xg[b * 12 + 8 + l15] + bi1n + rr * (gn + bh1n));
                    h1v = (1.f - zz) * nn + zz * hf[b * 1024 + j];
                    h1r_[r2] = h1v;
                }
                float h1o = __shfl(h1v, lane + 1, 64);
                if (l15 < 4 && (l15 & 1) == 0) {
                    bf16_t hS = (bf16_t)h1v, hO = (bf16_t)h1o;
                    size_t vo = ((size_t)t * 64 + b) * 1024 + j;
                    astore_pair(h1H + vo, hS, hO);
                    astore_pair(h1L + vo,
                                (bf16_t)(h1v - (float)hS), (bf16_t)(h1o - (float)hO));
                }
            }
        }
        gbar(flags, done, ++epoch, blk, tid);

        // ===== P1: [gh2 | q] = h1 @ [W_hh2 ; WqT]^T (split 3-term) =====
        if (wave < 4) {
            acc1 = (f32x4){0.f, 0.f, 0.f, 0.f};
            const int brow = wave * 16 + l15;
            const bf16_t* ah = h1H + ((size_t)t * 64 + brow) * 1024;
            const bf16_t* al = h1L + ((size_t)t * 64 + brow) * 1024;
            #pragma unroll 8
            for (int kk = 0; kk < 32; ++kk) {
                bf16x8 avh = *(const bf16x8*)(ah + kk * 32 + l4 * 8);
                bf16x8 avl = *(const bf16x8*)(al + kk * 32 + l4 * 8);
                int boff = (kk * 64 + l4 * 16) ^ ((l15 & 7) << 4);
                bf16x8 bvh = *(const bf16x8*)(sm + W2H_OFF + l15 * 2048 + boff);
                bf16x8 bvl = *(const bf16x8*)(sm + W2L_OFF + l15 * 2048 + boff);
                acc1 = __builtin_amdgcn_mfma_f32_16x16x32_bf16(avh, bvh, acc1, 0, 0, 0);
                acc1 = __builtin_amdgcn_mfma_f32_16x16x32_bf16(avl, bvh, acc1, 0, 0, 0);
                acc1 = __builtin_amdgcn_mfma_f32_16x16x32_bf16(avh, bvl, acc1, 0, 0, 0);
            }
            if (l15 >= 12) {
                int jq = blk4 + l15 - 12;
                #pragma unroll
                for (int r2 = 0; r2 < 4; ++r2)
                    astore_f32(&qgv[((size_t)t * 64 + (wave * 16 + l4 * 4 + r2)) * 1024 + jq],
                               acc1[r2]);
            }
        }
        gbar(flags, done, ++epoch, blk, tid);

        // ===== P2a: scores from register cacheK (s = aq*16 + wave) =====
        {
            const float* qrow = qgv + ((size_t)t * 64 + ab) * 1024;
            float sum = 0.f;
            #pragma unroll
            for (int i = 0; i < 16; ++i)
                sum += tanh_(qrow[lane + 64 * i] + bqreg[i] + ckreg[i]) * vreg[i];
            #pragma unroll
            for (int off = 32; off; off >>= 1) sum += __shfl_down(sum, off, 64);
            if (lane == 0) astore_f32(&scgv[(size_t)t * 4096 + ab * 64 + aq * 16 + wave], sum);
        }
        gbar(flags, done, ++epoch, blk, tid);

        // ===== P2b: softmax + PV from register ctx (1024 threads, 2/col) =====
        {
            const float* scrow = scgv + (size_t)t * 4096 + ab * 64;
            float v = (cmask[ab * 64 + lane] != 0) ? -3.4e38f : scrow[lane];
            float mx = v;
            #pragma unroll
            for (int off = 32; off; off >>= 1) mx = fmaxf(mx, __shfl_xor(mx, off, 64));
            float e = __expf(v - mx);
            float sden = e;
            #pragma unroll
            for (int off = 32; off; off >>= 1) sden += __shfl_xor(sden, off, 64);
            float prv = e / sden;

            float sum = 0.f;
            #pragma unroll
            for (int q = 0; q < 16; ++q) {
                float p0 = __shfl(prv, sbase + 2 * q, 64);
                float p1 = __shfl(prv, sbase + 2 * q + 1, 64);
                sum += p0 * __uint_as_float(cr[q] << 16);
                sum += p1 * __uint_as_float(cr[q] & 0xffff0000u);
            }
            sum += __shfl_xor(sum, 1, 64);
            if ((tid & 1) == 0)
                astore_f32(attnseq + ((size_t)ab * T_ + t) * 2048 + cmy, sum);
        }
        gbar(flags, done, ++epoch, blk, tid);

        // ===== P3: gi2 = attn @ W_ih2^T (A split, W hi) + GRU2 =====
        if (wave < 4) {
            f32x4 acc3 = {0.f, 0.f, 0.f, 0.f};
            const int brow = wave * 16 + l15;
            const float* aptr = attnseq + ((size_t)brow * T_ + t) * 2048;
            #pragma unroll 8
            for (int kk = 0; kk < 64; ++kk) {
                bf16x8 avh, avl;
                split8(aptr + kk * 32 + l4 * 8, avh, avl);
                bf16x8 bvh = *(const bf16x8*)(sm + W3H_OFF + l15 * 4096 +
                                              ((kk * 64 + l4 * 16) ^ ((l15 & 7) << 4)));
                acc3 = __builtin_amdgcn_mfma_f32_16x16x32_bf16(avh, bvh, acc3, 0, 0, 0);
                acc3 = __builtin_amdgcn_mfma_f32_16x16x32_bf16(avl, bvh, acc3, 0, 0, 0);
            }
            #pragma unroll
            for (int r2 = 0; r2 < 4; ++r2) {
                float ir  = acc3[r2];
                float iz  = __shfl(acc3[r2], (lane & 48) | (l15 + 4), 64);
                float in2 = __shfl(acc3[r2], (lane & 48) | (l15 + 8), 64);
                float hr  = acc1[r2];
                float hz  = __shfl(acc1[r2], (lane & 48) | (l15 + 4), 64);
                float hn  = __shfl(acc1[r2], (lane & 48) | (l15 + 8), 64);
                int b = wave * 16 + l4 * 4 + r2;
                if (l15 < 4) {
                    float rr = sigm_(ir + bi2r + hr + bh2r);
                    float zz = sigm_(iz + bi2z + hz + bh2z);
                    float nn = tanh_(in2 + bi2n + rr * (hn + bh2n));
                    float h2 = (1.f - zz) * nn + zz * h1r_[r2];
                    hf[b * 1024 + j] = h2;
                    astore_f32(&outseq[((size_t)b * T_ + t) * 1024 + j], h2);
                    if (t == T_ - 1) hfinal[b * 1024 + j] = h2;
                }
            }
        }
        gbar(flags, done, ++epoch, blk, tid);
    }
}

// ===================== final logits =====================
__global__ __launch_bounds__(256)
void final_kernel(const float* __restrict__ Lacc,
                  const float* __restrict__ bi, const float* __restrict__ bh,
                  const float* __restrict__ bc, float* __restrict__ out)
{
    int i = blockIdx.x * 256 + threadIdx.x;
    int e = i & 511;
    out[i] = tanh_(Lacc[i] + bi[e] + bh[e] + bc[e]);
}

// ===================== host =====================
extern "C" void kernel_launch(void* const* d_in, const int* in_sizes, int n_in,
                              void* d_out, int out_size, void* d_ws, size_t ws_size,
                              hipStream_t stream)
{
    const int*   y       = (const int*)  d_in[0];
    const float* context = (const float*)d_in[1];
    const int*   cmask   = (const int*)  d_in[2];
    const float* hidden  = (const float*)d_in[3];
    const float* emb     = (const float*)d_in[4];
    const float* W_ih1   = (const float*)d_in[5];
    const float* W_hh1   = (const float*)d_in[6];
    const float* b_ih1   = (const float*)d_in[7];
    const float* b_hh1   = (const float*)d_in[8];
    const float* Wq      = (const float*)d_in[9];
    const float* bq      = (const float*)d_in[10];
    const float* Wk      = (const float*)d_in[11];
    const float* v_attn  = (const float*)d_in[12];
    const float* W_ih2   = (const float*)d_in[13];
    const float* W_hh2   = (const float*)d_in[14];
    const float* b_ih2   = (const float*)d_in[15];
    const float* b_hh2   = (const float*)d_in[16];
    const float* Wi      = (const float*)d_in[17];
    const float* bi      = (const float*)d_in[18];
    const float* Wh      = (const float*)d_in[19];
    const float* bh      = (const float*)d_in[20];
    const float* Wc      = (const float*)d_in[21];
    const float* bc      = (const float*)d_in[22];

    char* ws = (char*)d_ws;
    size_t o = 0;
    auto alloc = [&](size_t bytes) { char* p = ws + o; o += (bytes + 255) & ~(size_t)255; return p; };
    unsigned* flags = (unsigned*)alloc(NBLK * FLSTR * 4);
    unsigned* done  = (unsigned*)alloc(8 * FLSTR * 4);
    float*  x       = (float*) alloc((size_t)2048 * 512 * 4);
    float*  WkT     = (float*) alloc((size_t)1024 * 2048 * 4);
    float*  WqT     = (float*) alloc((size_t)1024 * 1024 * 4);
    bf16_t* ctxb    = (bf16_t*)alloc((size_t)4096 * 2048 * 2);
    float*  xg2     = (float*) alloc((size_t)2048 * 3072 * 4);      // permuted Xg
    float*  Lacc    = (float*) alloc((size_t)2048 * 512 * 4);
    float*  cacheK  = (float*) alloc((size_t)4096 * 1024 * 4);
    float*  qgv     = (float*) alloc((size_t)T_ * 64 * 1024 * 4);
    float*  hf      = (float*) alloc((size_t)64 * 1024 * 4);
    bf16_t* h1H     = (bf16_t*)alloc((size_t)T_ * 64 * 1024 * 2);
    bf16_t* h1L     = (bf16_t*)alloc((size_t)T_ * 64 * 1024 * 2);
    float*  attnseq = (float*) alloc((size_t)2048 * 2048 * 4);
    float*  outseq  = (float*) alloc((size_t)2048 * 1024 * 4);
    float*  scgv    = (float*) alloc((size_t)T_ * 64 * 64 * 4);

    hipMemsetAsync(flags, 0, (NBLK * FLSTR + 8 * FLSTR) * 4, stream);

    embed_kernel<<<(B_*T_*E_/4 + 255)/256, 256, 0, stream>>>(y, emb, x);
    transpose_kernel<<<dim3(1024/32, 2048/32), dim3(32,32), 0, stream>>>(Wk, WkT, 2048, 1024);
    transpose_kernel<<<dim3(1024/32, 1024/32), dim3(32,32), 0, stream>>>(Wq, WqT, 1024, 1024);
    cvt_ctx<<<(4096*2048/8)/256, 256, 0, stream>>>(context, ctxb);

    sgemm<0, 1><<<dim3(G_/128, 16), 256, 0, stream>>>(x, W_ih1, xg2, G_, E_);   // Xg permuted
    sgemm<0, 0><<<dim3(E_/128, 16), 256, 0, stream>>>(x, Wi, Lacc, E_, E_);
    sgemm<0, 0><<<dim3(H_/128, 32), 256, 0, stream>>>(context, WkT, cacheK, H_, C_);

    hipFuncSetAttribute((const void*)scan_kernel, hipFuncAttributeMaxDynamicSharedMemorySize, SMEM_BYTES);
    scan_kernel<<<NBLK, 1024, SMEM_BYTES, stream>>>(
        W_hh1, W_hh2, WqT, W_ih2, xg2,
        b_ih1, b_hh1, b_ih2, b_hh2, bq, v_attn, cmask, hidden, cacheK, ctxb,
        qgv, hf, h1H, h1L, attnseq, outseq,
        (float*)d_out + (size_t)B_ * T_ * E_, scgv, flags, done);

    sgemm<1, 0><<<dim3(E_/128, 16), 256, 0, stream>>>(outseq, Wh, Lacc, E_, H_);
    sgemm<1, 0><<<dim3(E_/128, 16), 256, 0, stream>>>(attnseq, Wc, Lacc, E_, C_);

    final_kernel<<<(B_*T_*E_)/256, 256, 0, stream>>>(Lacc, bi, bh, bc, (float*)d_out);
}